// Round 13
// baseline (194.086 us; speedup 1.0000x reference)
//
#include <hip/hip_runtime.h>
#include <math.h>

#define EPSV 1e-5f

typedef __bf16 bf16;
using bf16x8 = __attribute__((ext_vector_type(8))) __bf16;
using bf16x4 = __attribute__((ext_vector_type(4))) __bf16;
using bf16x2 = __attribute__((ext_vector_type(2))) __bf16;
using f32x4  = __attribute__((ext_vector_type(4))) float;

static __device__ __forceinline__ f32x4 mfma16(bf16x8 a, bf16x8 b, f32x4 c) {
    return __builtin_amdgcn_mfma_f32_16x16x32_bf16(a, b, c, 0, 0, 0);
}
static __device__ __forceinline__ f32x4 zero4() {
    f32x4 z = {0.f, 0.f, 0.f, 0.f};
    return z;
}

// async global->LDS, 16B per lane. LDS dst = wave-uniform base + lane*16;
// global src is per-lane.
typedef __attribute__((address_space(1))) const char g_char_t;
typedef __attribute__((address_space(3))) char lds_char_t;
static __device__ __forceinline__ void gll16(const void* g, void* l) {
    __builtin_amdgcn_global_load_lds((g_char_t*)g, (lds_char_t*)l, 16, 0, 0);
}

// exact-GELU via Abramowitz-Stegun 7.1.26 erf (|err| <= 1.5e-7)
static __device__ __forceinline__ float gelu_f(float v) {
    float z = fabsf(v) * 0.70710678118f;
    float t = __builtin_amdgcn_rcpf(1.f + 0.3275911f * z);
    float poly = t * (0.254829592f + t * (-0.284496736f + t * (1.421413741f +
                 t * (-1.453152027f + t * 1.061405429f))));
    float e = __expf(-z * z);
    float erfv = copysignf(1.f - poly * e, v);
    return 0.5f * v * (1.f + erfv);
}

// ---------------------------------------------------------------------------
// Merged weight prep (1 dispatch) + zb zeroing.
// conv3x3 fp32 [cout][CIN][3][3] -> bf16 lane-linear fragments
//   wt[(((kgt*NC+cci)*4 + mi)*64 + lg*16+lix)*8 + j]
// gc_w fp32 [128][128] -> wt[(((ks*4+lg)*128)+cout)*8+j]
// ---------------------------------------------------------------------------
static __device__ __forceinline__ void prep3x3_one(const float* w, bf16* wt,
                                                   int t, int CIN)
{
    int cout = t / CIN, ci = t - cout * CIN;
    int cci = ci >> 5, lg = (ci >> 3) & 3, j = ci & 7;
    int mi = cout >> 4, lix = cout & 15;
#pragma unroll
    for (int kgt = 0; kgt < 9; ++kgt) {
        float v = w[(size_t)t * 9 + kgt];
        wt[((((size_t)kgt * (CIN >> 5) + cci) * 4 + mi) * 64 + lg * 16 + lix) * 8 + j]
            = (bf16)v;
    }
}

__global__ __launch_bounds__(256) void prep_all(
    const float* __restrict__ fc1_w, const float* __restrict__ fc2_w,
    const float* __restrict__ gc_w,
    bf16* __restrict__ wt1, bf16* __restrict__ wt2, bf16* __restrict__ wtg,
    float* __restrict__ zb)
{
    int bx = blockIdx.x, tid = threadIdx.x;
    if (bx < 16) {
        prep3x3_one(fc1_w, wt1, bx * 256 + tid, 64);
    } else if (bx < 48) {
        prep3x3_one(fc2_w, wt2, (bx - 16) * 256 + tid, 128);
    } else {
        if (bx == 48 && tid < 64)
            ((float4*)zb)[tid] = make_float4(0.f, 0.f, 0.f, 0.f);
        int t = (bx - 48) * 256 + tid;           // cout*128+ci, 16384
        int cout = t >> 7, ci = t & 127;
        int ks = ci >> 5, lg = (ci >> 3) & 3, j = ci & 7;
        wtg[(((size_t)(ks * 4 + lg) * 128) + cout) * 8 + j] = (bf16)gc_w[t];
    }
}

// ---------------------------------------------------------------------------
// conv3x3 MFMA implicit GEMM v13 (v11 compute structure, best measured).
// Block = 512 thr = 8 waves; wave = one y-row, tile = 8 rows x 64 px,
// wave tile 64 cout x 64 px (mi=4, nj=4). Input LDS swizzled
// (s(pix)=(pix&3)^((pix>>2)&3), both-sides, linear dest).
// INMODE 0: input bf16 NHWC via gll16 (counted vmcnt, raw barriers).
// INMODE 1: input fp32 NCHW via reg-staging (fused x->bf16 conversion;
//           T14 issue-early/write-late; vmcnt(0) per chunk - schedule
//           proven non-critical across v5..v12).
// OUTMODE 0: bf16 NHWC h + BN, coalesced LDS-staged store + fused q-gather.
// OUTMODE 1: fp32 NCHW + BN + residual read from fp32 NCHW x (same index).
// ---------------------------------------------------------------------------
template<int CIN, int INMODE, int OUTMODE>
__global__ __launch_bounds__(512) void conv3x3_mfma(
    const void* __restrict__ inp, const bf16* __restrict__ wt,
    const float* __restrict__ bias,
    const float* __restrict__ bg, const float* __restrict__ bb,
    const float* __restrict__ bm, const float* __restrict__ bv,
    const float* __restrict__ xres, const bf16* __restrict__ zb,
    void* __restrict__ outp, bf16* __restrict__ qout)
{
    constexpr int NC = CIN >> 5;
    __shared__ bf16 in_lds[2][672 * 32];      // 86,016 B
    __shared__ bf16 w_lds[2][36 * 512];       // 73,728 B  (total 159,744)

    const int wg = blockIdx.x;                // 512 blocks
    const int v  = (wg & 7) * 64 + (wg >> 3); // bijective XCD chunking
    const int tile = v & 31, b = v >> 5;
    const int x0 = (tile & 1) * 64;
    const int y0 = (tile >> 1) * 8;
    const int tid  = threadIdx.x;
    const int wid  = tid >> 6;
    const int lane = tid & 63;
    const int lix  = lane & 15, lg = lane >> 4;

    // staging geometry: 42 wave-chunks of 64 lanes x 16B; wave w owns {w,w+8,..}
    // source unit swizzled by s(pix) so the linear LDS tile is pre-permuted.
    size_t goff[6]; bool gok[6];
#pragma unroll
    for (int i = 0; i < 6; ++i) {
        int chunk = wid + 8 * i;
        int f = chunk * 64 + lane;
        int pix = f >> 2, u = f & 3;
        int sw = (pix & 3) ^ ((pix >> 2) & 3);
        int ug = u ^ sw;
        int iy = pix / 66, ix = pix - iy * 66;
        int gy = y0 + iy - 1, gx = x0 + ix - 1;
        gok[i]  = (chunk < 42) && (pix < 660) &&
                  (unsigned)gy < 128u && (unsigned)gx < 128u;
        if (INMODE == 0)
            goff[i] = (size_t)((b * 128 + gy) * 128 + gx) * CIN + ug * 8;
        else
            goff[i] = ((size_t)(b * CIN + ug * 8) << 14) + (gy << 7) + gx;
    }
    // bfr read bases (elements): pixel p -> p*32 + (lg^s(p))*8; nj adds 512
    int rd[9];
#pragma unroll
    for (int kg = 0; kg < 3; ++kg)
#pragma unroll
        for (int t = 0; t < 3; ++t) {
            int pix0 = (wid + kg) * 66 + lix + t;
            int sw = (pix0 & 3) ^ ((pix0 >> 2) & 3);
            rd[kg * 3 + t] = pix0 * 32 + ((lg ^ sw) << 3);
        }

    f32x4 acc[4][4];
#pragma unroll
    for (int i = 0; i < 4; ++i)
#pragma unroll
        for (int j = 0; j < 4; ++j) acc[i][j] = zero4();

    const bf16* inb = (const bf16*)inp;
    const float* inf = (const float*)inp;
    float fr[6][8];

    auto issue_in = [&](int cci, int buf) {     // INMODE 0
#pragma unroll
        for (int i = 0; i < 6; ++i) {
            int chunk = wid + 8 * i;
            if (chunk < 42) {
                const void* src = gok[i] ? (const void*)(inb + goff[i] + cci * 32)
                                         : (const void*)zb;
                gll16(src, (char*)&in_lds[buf][0] + chunk * 1024);
            }
        }
    };
    auto stage_load = [&](int cci) {            // INMODE 1: fp32 NCHW -> regs
#pragma unroll
        for (int i = 0; i < 6; ++i) {
#pragma unroll
            for (int j = 0; j < 8; ++j)
                fr[i][j] = gok[i]
                    ? inf[goff[i] + ((size_t)cci << 19) + ((size_t)j << 14)]
                    : 0.f;
        }
    };
    auto stage_write = [&](int buf) {           // INMODE 1: regs -> LDS bf16
#pragma unroll
        for (int i = 0; i < 6; ++i) {
            int chunk = wid + 8 * i;
            if (chunk < 42) {
                bf16x8 vv;
#pragma unroll
                for (int j = 0; j < 8; ++j) vv[j] = (bf16)fr[i][j];
                *(bf16x8*)&in_lds[buf][chunk * 512 + lane * 8] = vv;
            }
        }
    };
    auto issue_w = [&](int cci, int buf) {
#pragma unroll
        for (int i = 0; i < 5; ++i) {
            int chunk = wid + 8 * i;              // = kgt*4 + mi
            if (chunk < 36) {
                const bf16* src = wt + ((size_t)(chunk >> 2) * NC + cci) * 2048
                                     + (chunk & 3) * 512 + lane * 8;
                gll16(src, (char*)&w_lds[buf][0] + chunk * 1024);
            }
        }
    };
    // rotated-register pipelined compute (v11): issue kgt+1's frag loads
    // before kgt's MFMAs; sched_barrier(0) pins the phase boundaries.
    auto compute = [&](int buf) {
        bf16x8 afA[4], bfA[4], afB[4], bfB[4];
#pragma unroll
        for (int mi = 0; mi < 4; ++mi)
            afA[mi] = *(const bf16x8*)&w_lds[buf][(0 * 4 + mi) * 512 + lane * 8];
#pragma unroll
        for (int nj = 0; nj < 4; ++nj)
            bfA[nj] = *(const bf16x8*)&in_lds[buf][rd[0] + nj * 512];
#pragma unroll
        for (int kgt = 0; kgt < 9; ++kgt) {
            bf16x8* afC = (kgt & 1) ? afB : afA;
            bf16x8* bfC = (kgt & 1) ? bfB : bfA;
            bf16x8* afN = (kgt & 1) ? afA : afB;
            bf16x8* bfN = (kgt & 1) ? bfA : bfB;
            if (kgt < 8) {
#pragma unroll
                for (int mi = 0; mi < 4; ++mi)
                    afN[mi] = *(const bf16x8*)&w_lds[buf][((kgt + 1) * 4 + mi) * 512 + lane * 8];
#pragma unroll
                for (int nj = 0; nj < 4; ++nj)
                    bfN[nj] = *(const bf16x8*)&in_lds[buf][rd[kgt + 1] + nj * 512];
            }
            __builtin_amdgcn_sched_barrier(0);
#pragma unroll
            for (int nj = 0; nj < 4; ++nj)
#pragma unroll
                for (int mi = 0; mi < 4; ++mi)
                    acc[mi][nj] = mfma16(afC[mi], bfC[nj], acc[mi][nj]);
            __builtin_amdgcn_sched_barrier(0);
        }
    };

    if constexpr (INMODE == 0) {
        issue_in(0, 0);
        issue_w(0, 0);
#pragma unroll 1
        for (int c = 0; c < NC; ++c) {
            if (c + 1 < NC) {
                issue_in(c + 1, (c + 1) & 1);
                issue_w(c + 1, (c + 1) & 1);
                // wait for chunk c's loads only: chunk c+1's newest 11/10/9
                // stay in flight across the barrier (T4).
                if (wid < 2)      asm volatile("s_waitcnt vmcnt(11)" ::: "memory");
                else if (wid < 4) asm volatile("s_waitcnt vmcnt(10)" ::: "memory");
                else              asm volatile("s_waitcnt vmcnt(9)"  ::: "memory");
            } else {
                asm volatile("s_waitcnt vmcnt(0)" ::: "memory");
            }
            __builtin_amdgcn_s_barrier();       // raw: no implicit vmcnt drain
            __builtin_amdgcn_sched_barrier(0);
            compute(c & 1);
            __builtin_amdgcn_s_barrier();       // buf reusable next iteration
        }
    } else {
        stage_load(0);
        stage_write(0);
        issue_w(0, 0);
#pragma unroll 1
        for (int c = 0; c < NC; ++c) {
            if (c + 1 < NC) {
                issue_w(c + 1, (c + 1) & 1);
                stage_load(c + 1);              // issue-early (regs)
            }
            asm volatile("s_waitcnt vmcnt(0)" ::: "memory");
            asm volatile("s_waitcnt lgkmcnt(0)" ::: "memory");
            __builtin_amdgcn_s_barrier();
            __builtin_amdgcn_sched_barrier(0);
            compute(c & 1);
            if (c + 1 < NC) stage_write((c + 1) & 1);   // write-late
            __builtin_amdgcn_s_barrier();
        }
    }

    if (OUTMODE == 0) {
        // single-pass coalesced store: stage all 8 rows across both in bufs
        bf16* out = (bf16*)outp;
        bf16* stg = &in_lds[0][0];             // [8*64 px][68], 69,632 B
#pragma unroll
        for (int mi = 0; mi < 4; ++mi) {
            float A[4], Bc[4];
#pragma unroll
            for (int r = 0; r < 4; ++r) {
                int c = mi * 16 + lg * 4 + r;
                float s = bg[c] * rsqrtf(bv[c] + EPSV);
                A[r]  = s;
                Bc[r] = bias[c] * s + bb[c] - bm[c] * s;
            }
#pragma unroll
            for (int nj = 0; nj < 4; ++nj) {
                int px = nj * 16 + lix;
                bf16x4 vv;
#pragma unroll
                for (int r = 0; r < 4; ++r)
                    vv[r] = (bf16)(acc[mi][nj][r] * A[r] + Bc[r]);
                *(bf16x4*)&stg[(wid * 64 + px) * 68 + mi * 16 + lg * 4] = vv;
            }
        }
        __syncthreads();
#pragma unroll
        for (int k = 0; k < 8; ++k) {
            int idx = k * 512 + tid;           // 4096 16B-units
            int row = idx >> 9, rem = idx & 511;
            int px = rem >> 3, cu = rem & 7;
            bf16x8 vv = *(const bf16x8*)&stg[(row * 64 + px) * 68 + cu * 8];
            *(bf16x8*)&out[((size_t)((b * 128 + y0 + row) * 128)
                            + x0 + px) * 64 + cu * 8] = vv;
        }
        // fused q-gather: q[b][n][c] = h[b][4*(n/32)][4*(n%32)][c]
        if (qout && tid < 256) {
            int row4 = (tid >> 7) * 4;          // 0 or 4
            int rem  = tid & 127;               // 16 px4 * 8 cu
            int px4  = (rem >> 3) * 4, cu = rem & 7;
            int gy = y0 + row4, gx = x0 + px4;
            int n = ((gy >> 2) << 5) + (gx >> 2);
            bf16x8 vv = *(const bf16x8*)&stg[(row4 * 64 + px4) * 68 + cu * 8];
            *(bf16x8*)&qout[((size_t)(b * 1024 + n)) * 64 + cu * 8] = vv;
        }
    } else {
        float* out = (float*)outp;
        const int gy = y0 + wid;
#pragma unroll
        for (int mi = 0; mi < 4; ++mi) {
            float A[4], Bc[4];
#pragma unroll
            for (int r = 0; r < 4; ++r) {
                int c = mi * 16 + lg * 4 + r;
                float s = bg[c] * rsqrtf(bv[c] + EPSV);
                A[r]  = s;
                Bc[r] = bias[c] * s + bb[c] - bm[c] * s;
            }
#pragma unroll
            for (int nj = 0; nj < 4; ++nj) {
                int px = x0 + nj * 16 + lix;
#pragma unroll
                for (int r = 0; r < 4; ++r) {
                    int c = mi * 16 + lg * 4 + r;
                    size_t oi = ((size_t)(b * 64 + c) << 14) + (gy << 7) + px;
                    out[oi] = acc[mi][nj][r] * A[r] + Bc[r] + xres[oi];
                }
            }
        }
    }
}

// ---------------------------------------------------------------------------
// Fused flash attention (unchanged).
// ---------------------------------------------------------------------------
__global__ __launch_bounds__(256) void attn_fused(const bf16* __restrict__ q,
                                                  bf16* __restrict__ o)
{
    __shared__ bf16 qn[64 * 72];
    __shared__ bf16 kn[128 * 72];
    __shared__ bf16 vt[64 * 136];
    __shared__ bf16 pl[4][16 * 136];
    __shared__ __align__(16) float fac[4][16];
    const int n0 = blockIdx.x * 64, b = blockIdx.y;
    const int tid = threadIdx.x, w = tid >> 6, lane = tid & 63;
    const int lix = lane & 15, lg = lane >> 4;
    const bf16* qb = q + ((size_t)b << 16);

    for (int f = tid; f < 512; f += 256) {
        int row = f >> 3, cu = f & 7;
        *(bf16x8*)&qn[row * 72 + cu * 8] =
            *(const bf16x8*)&qb[(size_t)(n0 + row) * 64 + cu * 8];
    }

    float m_run = -3.0e38f, l_run = 0.f;
    f32x4 oacc[4];
#pragma unroll
    for (int ct = 0; ct < 4; ++ct) oacc[ct] = zero4();

    for (int mt = 0; mt < 1024; mt += 128) {
        __syncthreads();
        for (int f = tid; f < 1024; f += 256) {
            int row = f >> 3, cu = f & 7;
            *(bf16x8*)&kn[row * 72 + cu * 8] =
                *(const bf16x8*)&qb[(size_t)(mt + row) * 64 + cu * 8];
        }
        for (int f = tid; f < 512; f += 256) {
            int mp = f >> 3, cu = f & 7;
            int m = mp * 2;
            bf16x8 a = *(const bf16x8*)&qb[(size_t)(mt + m) * 64 + cu * 8];
            bf16x8 c = *(const bf16x8*)&qb[(size_t)(mt + m + 1) * 64 + cu * 8];
#pragma unroll
            for (int j = 0; j < 8; ++j) {
                bf16x2 pr = {a[j], c[j]};
                *(bf16x2*)&vt[(cu * 8 + j) * 136 + m] = pr;
            }
        }
        __syncthreads();

        bf16x8 bq0 = *(const bf16x8*)&qn[(w * 16 + lix) * 72 + lg * 8];
        bf16x8 bq1 = *(const bf16x8*)&qn[(w * 16 + lix) * 72 + 32 + lg * 8];

        f32x4 s[8];
#pragma unroll
        for (int t = 0; t < 8; ++t) {
            bf16x8 a0 = *(const bf16x8*)&kn[(t * 16 + lix) * 72 + lg * 8];
            bf16x8 a1 = *(const bf16x8*)&kn[(t * 16 + lix) * 72 + 32 + lg * 8];
            s[t] = mfma16(a0, bq0, zero4());
            s[t] = mfma16(a1, bq1, s[t]);
        }

        float mx = -3.0e38f;
#pragma unroll
        for (int t = 0; t < 8; ++t)
#pragma unroll
            for (int r = 0; r < 4; ++r) { s[t][r] *= 0.125f; mx = fmaxf(mx, s[t][r]); }
        mx = fmaxf(mx, __shfl_xor(mx, 16));
        mx = fmaxf(mx, __shfl_xor(mx, 32));
        float m_new = fmaxf(m_run, mx);
        float alpha = __expf(m_run - m_new);

        float psum = 0.f;
#pragma unroll
        for (int t = 0; t < 8; ++t) {
            float p0 = __expf(s[t][0] - m_new), p1 = __expf(s[t][1] - m_new);
            float p2 = __expf(s[t][2] - m_new), p3 = __expf(s[t][3] - m_new);
            psum += (p0 + p1) + (p2 + p3);
            bf16x2 v01 = {(bf16)p0, (bf16)p1};
            bf16x2 v23 = {(bf16)p2, (bf16)p3};
            *(bf16x2*)&pl[w][lix * 136 + t * 16 + lg * 4]     = v01;
            *(bf16x2*)&pl[w][lix * 136 + t * 16 + lg * 4 + 2] = v23;
        }
        psum += __shfl_xor(psum, 16);
        psum += __shfl_xor(psum, 32);
        l_run = l_run * alpha + psum;
        m_run = m_new;
        if (lg == 0) fac[w][lix] = alpha;

        float4 a4 = *(const float4*)&fac[w][lg * 4];
        float aa[4] = {a4.x, a4.y, a4.z, a4.w};
#pragma unroll
        for (int ct = 0; ct < 4; ++ct)
#pragma unroll
            for (int r = 0; r < 4; ++r) oacc[ct][r] *= aa[r];

#pragma unroll
        for (int kk = 0; kk < 4; ++kk) {
            bf16x8 pa = *(const bf16x8*)&pl[w][lix * 136 + kk * 32 + lg * 8];
#pragma unroll
            for (int ct = 0; ct < 4; ++ct) {
                bf16x8 bv = *(const bf16x8*)&vt[(ct * 16 + lix) * 136 + kk * 32 + lg * 8];
                oacc[ct] = mfma16(pa, bv, oacc[ct]);
            }
        }
    }

    if (lg == 0) fac[w][lix] = l_run;
    float4 l4 = *(const float4*)&fac[w][lg * 4];
    float ll[4] = {1.f / l4.x, 1.f / l4.y, 1.f / l4.z, 1.f / l4.w};
#pragma unroll
    for (int ct = 0; ct < 4; ++ct)
#pragma unroll
        for (int r = 0; r < 4; ++r) {
            int n = n0 + w * 16 + lg * 4 + r;
            int c = ct * 16 + lix;
            o[((size_t)(b * 1024 + n)) * 64 + c] = (bf16)(oacc[ct][r] * ll[r]);
        }
}

// ---------------------------------------------------------------------------
// conv1x1 (128->128) + BN + fast exact GELU; coalesced store via LDS.
// ---------------------------------------------------------------------------
__global__ __launch_bounds__(256) void conv1x1_mfma(
    const bf16* __restrict__ h, const bf16* __restrict__ ov,
    const bf16* __restrict__ wt, const float* __restrict__ bias,
    const float* __restrict__ bg, const float* __restrict__ bb,
    const float* __restrict__ bm, const float* __restrict__ bv,
    bf16* __restrict__ g)
{
    __shared__ bf16 in1[128 * 136];           // 34,816 B (reused as out-stage)
    const int y = blockIdx.x, b = blockIdx.y;
    const int tid = threadIdx.x;
    const int wid = tid >> 6, lane = tid & 63;
    const int lix = lane & 15, lg = lane >> 4;
    const int wm = wid >> 1, wn = wid & 1;

    for (int f = tid; f < 128 * 16; f += 256) {
        int px = f >> 4, cu = f & 15;
        bf16x8 v;
        if (cu < 8) {
            v = *(const bf16x8*)&h[((size_t)((b * 128 + y) * 128 + px)) * 64 + cu * 8];
        } else {
            int n = ((y >> 2) << 5) + (px >> 2);
            v = *(const bf16x8*)&ov[((size_t)(b * 1024 + n)) * 64 + (cu - 8) * 8];
        }
        *(bf16x8*)&in1[px * 136 + cu * 8] = v;
    }
    __syncthreads();

    f32x4 acc[4][4];
#pragma unroll
    for (int i = 0; i < 4; ++i)
#pragma unroll
        for (int j = 0; j < 4; ++j) acc[i][j] = zero4();

#pragma unroll
    for (int ks = 0; ks < 4; ++ks) {
        bf16x8 af[4], bfv[4];
#pragma unroll
        for (int mi = 0; mi < 4; ++mi)
            af[mi] = *(const bf16x8*)&wt[(((size_t)(ks * 4 + lg) * 128) + wm * 64 + mi * 16 + lix) * 8];
#pragma unroll
        for (int nj = 0; nj < 4; ++nj)
            bfv[nj] = *(const bf16x8*)&in1[(wn * 64 + nj * 16 + lix) * 136 + ks * 32 + lg * 8];
#pragma unroll
        for (int mi = 0; mi < 4; ++mi)
#pragma unroll
            for (int nj = 0; nj < 4; ++nj)
                acc[mi][nj] = mfma16(af[mi], bfv[nj], acc[mi][nj]);
    }

    __syncthreads();                           // done reading in1
    bf16* stg = in1;                           // [128 px][132] view
#pragma unroll
    for (int mi = 0; mi < 4; ++mi) {
        float A[4], Bc[4];
#pragma unroll
        for (int r = 0; r < 4; ++r) {
            int c = wm * 64 + mi * 16 + lg * 4 + r;
            float s = bg[c] * rsqrtf(bv[c] + EPSV);
            A[r]  = s;
            Bc[r] = bias[c] * s + bb[c] - bm[c] * s;
        }
#pragma unroll
        for (int nj = 0; nj < 4; ++nj) {
            int px = wn * 64 + nj * 16 + lix;
            bf16x4 vv;
#pragma unroll
            for (int r = 0; r < 4; ++r)
                vv[r] = (bf16)gelu_f(acc[mi][nj][r] * A[r] + Bc[r]);
            *(bf16x4*)&stg[px * 132 + wm * 64 + mi * 16 + lg * 4] = vv;
        }
    }
    __syncthreads();
#pragma unroll
    for (int k = 0; k < 8; ++k) {
        int idx = k * 256 + tid;               // 2048 16B-units
        int px = idx >> 4, cu = idx & 15;
        bf16x8 v = *(const bf16x8*)&stg[px * 132 + cu * 8];
        *(bf16x8*)&g[((size_t)((b * 128 + y) * 128) + px) * 128 + cu * 8] = v;
    }
}

// ---------------------------------------------------------------------------
extern "C" void kernel_launch(void* const* d_in, const int* in_sizes, int n_in,
                              void* d_out, int out_size, void* d_ws, size_t ws_size,
                              hipStream_t stream)
{
    const float* x     = (const float*)d_in[0];
    const float* fc1_w = (const float*)d_in[1];
    const float* fc1_b = (const float*)d_in[2];
    const float* bn1_g = (const float*)d_in[3];
    const float* bn1_b = (const float*)d_in[4];
    const float* bn1_m = (const float*)d_in[5];
    const float* bn1_v = (const float*)d_in[6];
    const float* gc_w  = (const float*)d_in[7];
    const float* gc_b  = (const float*)d_in[8];
    const float* bng_g = (const float*)d_in[9];
    const float* bng_b = (const float*)d_in[10];
    const float* bng_m = (const float*)d_in[11];
    const float* bng_v = (const float*)d_in[12];
    const float* fc2_w = (const float*)d_in[13];
    const float* fc2_b = (const float*)d_in[14];
    const float* bn2_g = (const float*)d_in[15];
    const float* bn2_b = (const float*)d_in[16];
    const float* bn2_m = (const float*)d_in[17];
    const float* bn2_v = (const float*)d_in[18];

    char* wsb = (char*)d_ws;
    bf16* h    = (bf16*)wsb;                      // 33,554,432 B
    bf16* g    = (bf16*)(wsb + 33554432);         // 67,108,864 B
    bf16* q    = (bf16*)(wsb + 100663296);        //  2,097,152 B
    bf16* o    = (bf16*)(wsb + 102760448);        //  2,097,152 B
    bf16* wt1  = (bf16*)(wsb + 104857600);        //     73,728 B
    bf16* wt2  = (bf16*)(wsb + 104931328);        //    147,456 B
    bf16* wtg  = (bf16*)(wsb + 105078784);        //     32,768 B
    bf16* zb   = (bf16*)(wsb + 105111552);        //      1,024 B

    prep_all<<<112, 256, 0, stream>>>(fc1_w, fc2_w, gc_w, wt1, wt2, wtg,
                                      (float*)zb);

    conv3x3_mfma<64, 1, 0><<<512, 512, 0, stream>>>(
        x, wt1, fc1_b, bn1_g, bn1_b, bn1_m, bn1_v, nullptr, zb, h, q);

    attn_fused<<<dim3(16, 16), 256, 0, stream>>>(q, o);

    conv1x1_mfma<<<dim3(128, 16), 256, 0, stream>>>(
        h, o, wtg, gc_b, bng_g, bng_b, bng_m, bng_v, g);

    conv3x3_mfma<128, 0, 1><<<512, 512, 0, stream>>>(
        g, wt2, fc2_b, bn2_g, bn2_b, bn2_m, bn2_v, x, zb, (float*)d_out, nullptr);
}

// Round 14
// 179.418 us; speedup vs baseline: 1.0818x; 1.0818x over previous
//
#include <hip/hip_runtime.h>
#include <math.h>

#define EPSV 1e-5f

typedef __bf16 bf16;
using bf16x8 = __attribute__((ext_vector_type(8))) __bf16;
using bf16x4 = __attribute__((ext_vector_type(4))) __bf16;
using bf16x2 = __attribute__((ext_vector_type(2))) __bf16;
using f32x4  = __attribute__((ext_vector_type(4))) float;

static __device__ __forceinline__ f32x4 mfma16(bf16x8 a, bf16x8 b, f32x4 c) {
    return __builtin_amdgcn_mfma_f32_16x16x32_bf16(a, b, c, 0, 0, 0);
}
static __device__ __forceinline__ f32x4 zero4() {
    f32x4 z = {0.f, 0.f, 0.f, 0.f};
    return z;
}

// async global->LDS, 16B per lane. LDS dst = wave-uniform base + lane*16;
// global src is per-lane.
typedef __attribute__((address_space(1))) const char g_char_t;
typedef __attribute__((address_space(3))) char lds_char_t;
static __device__ __forceinline__ void gll16(const void* g, void* l) {
    __builtin_amdgcn_global_load_lds((g_char_t*)g, (lds_char_t*)l, 16, 0, 0);
}

// exact-GELU via Abramowitz-Stegun 7.1.26 erf (|err| <= 1.5e-7)
static __device__ __forceinline__ float gelu_f(float v) {
    float z = fabsf(v) * 0.70710678118f;
    float t = __builtin_amdgcn_rcpf(1.f + 0.3275911f * z);
    float poly = t * (0.254829592f + t * (-0.284496736f + t * (1.421413741f +
                 t * (-1.453152027f + t * 1.061405429f))));
    float e = __expf(-z * z);
    float erfv = copysignf(1.f - poly * e, v);
    return 0.5f * v * (1.f + erfv);
}

// ---------------------------------------------------------------------------
// Merged weight prep (1 dispatch) + zb zeroing.
// ---------------------------------------------------------------------------
static __device__ __forceinline__ void prep3x3_one(const float* w, bf16* wt,
                                                   int t, int CIN)
{
    int cout = t / CIN, ci = t - cout * CIN;
    int cci = ci >> 5, lg = (ci >> 3) & 3, j = ci & 7;
    int mi = cout >> 4, lix = cout & 15;
#pragma unroll
    for (int kgt = 0; kgt < 9; ++kgt) {
        float v = w[(size_t)t * 9 + kgt];
        wt[((((size_t)kgt * (CIN >> 5) + cci) * 4 + mi) * 64 + lg * 16 + lix) * 8 + j]
            = (bf16)v;
    }
}

__global__ __launch_bounds__(256) void prep_all(
    const float* __restrict__ fc1_w, const float* __restrict__ fc2_w,
    const float* __restrict__ gc_w,
    bf16* __restrict__ wt1, bf16* __restrict__ wt2, bf16* __restrict__ wtg,
    float* __restrict__ zb)
{
    int bx = blockIdx.x, tid = threadIdx.x;
    if (bx < 16) {
        prep3x3_one(fc1_w, wt1, bx * 256 + tid, 64);
    } else if (bx < 48) {
        prep3x3_one(fc2_w, wt2, (bx - 16) * 256 + tid, 128);
    } else {
        if (bx == 48 && tid < 64)
            ((float4*)zb)[tid] = make_float4(0.f, 0.f, 0.f, 0.f);
        int t = (bx - 48) * 256 + tid;           // cout*128+ci, 16384
        int cout = t >> 7, ci = t & 127;
        int ks = ci >> 5, lg = (ci >> 3) & 3, j = ci & 7;
        wtg[(((size_t)(ks * 4 + lg) * 128) + cout) * 8 + j] = (bf16)gc_w[t];
    }
}

// ---------------------------------------------------------------------------
// x fp32 NCHW -> bf16 NHWC (LDS-transposed, coalesced both sides).
// ---------------------------------------------------------------------------
__global__ __launch_bounds__(256) void cvt_x_nhwc(const float* __restrict__ x,
                                                  bf16* __restrict__ xb)
{
    __shared__ float t_lds[64 * 68];
    const int bx = blockIdx.x;          // y = bx>>1, half = bx&1
    const int b  = blockIdx.y;
    const int y  = bx >> 1, x0 = (bx & 1) * 64;
    const int tid = threadIdx.x;

    for (int f = tid; f < 64 * 16; f += 256) {
        int c = f >> 4, xu = f & 15;
        float4 v = *(const float4*)&x[((size_t)(b * 64 + c) << 14) + (y << 7) + x0 + xu * 4];
        t_lds[(xu * 4 + 0) * 68 + c] = v.x;
        t_lds[(xu * 4 + 1) * 68 + c] = v.y;
        t_lds[(xu * 4 + 2) * 68 + c] = v.z;
        t_lds[(xu * 4 + 3) * 68 + c] = v.w;
    }
    __syncthreads();
    for (int f = tid; f < 64 * 8; f += 256) {
        int xx = f >> 3, cu = f & 7;
        const float* p = &t_lds[xx * 68 + cu * 8];
        bf16x8 v;
#pragma unroll
        for (int j = 0; j < 8; ++j) v[j] = (bf16)p[j];
        *(bf16x8*)&xb[((size_t)((b * 128 + y) * 128) + x0 + xx) * 64 + cu * 8] = v;
    }
}

// ---------------------------------------------------------------------------
// conv3x3 MFMA implicit GEMM (v11 structure - measured best).
// Block = 512 thr = 8 waves; wave = one y-row, tile = 8 rows x 64 px,
// wave tile 64 cout x 64 px (mi=4, nj=4). Input bf16 NHWC via gll16
// (counted vmcnt, raw barriers, T4); weights LDS-staged lane-linear;
// rotated-register per-kgt frag pipeline; input LDS swizzled
// (s(pix)=(pix&3)^((pix>>2)&3), both-sides, linear dest).
// OUTMODE 0: bf16 NHWC h + BN, coalesced LDS-staged store + fused q-gather.
// OUTMODE 1: fp32 NCHW + BN + residual (bf16 NHWC x_bf).
// ---------------------------------------------------------------------------
template<int CIN, int OUTMODE>
__global__ __launch_bounds__(512) void conv3x3_mfma(
    const bf16* __restrict__ in, const bf16* __restrict__ wt,
    const float* __restrict__ bias,
    const float* __restrict__ bg, const float* __restrict__ bb,
    const float* __restrict__ bm, const float* __restrict__ bv,
    const bf16* __restrict__ resid, const bf16* __restrict__ zb,
    void* __restrict__ outp, bf16* __restrict__ qout)
{
    constexpr int NC = CIN >> 5;
    __shared__ bf16 in_lds[2][672 * 32];      // 86,016 B
    __shared__ bf16 w_lds[2][36 * 512];       // 73,728 B  (total 159,744)

    const int wg = blockIdx.x;                // 512 blocks
    const int v  = (wg & 7) * 64 + (wg >> 3); // bijective XCD chunking
    const int tile = v & 31, b = v >> 5;
    const int x0 = (tile & 1) * 64;
    const int y0 = (tile >> 1) * 8;
    const int tid  = threadIdx.x;
    const int wid  = tid >> 6;
    const int lane = tid & 63;
    const int lix  = lane & 15, lg = lane >> 4;

    // staging: 42 wave-chunks of 64 lanes x 16B; wave w owns {w, w+8, ...}
    // source unit swizzled by s(pix) so the linear LDS tile is pre-permuted.
    int goff[6]; bool gok[6];
#pragma unroll
    for (int i = 0; i < 6; ++i) {
        int chunk = wid + 8 * i;
        int f = chunk * 64 + lane;
        int pix = f >> 2, u = f & 3;
        int sw = (pix & 3) ^ ((pix >> 2) & 3);
        int ug = u ^ sw;
        int iy = pix / 66, ix = pix - iy * 66;
        int gy = y0 + iy - 1, gx = x0 + ix - 1;
        gok[i]  = (chunk < 42) && (pix < 660) &&
                  (unsigned)gy < 128u && (unsigned)gx < 128u;
        goff[i] = ((b * 128 + gy) * 128 + gx) * CIN + ug * 8;
    }
    // bfr read bases (elements): pixel p -> p*32 + (lg^s(p))*8; nj adds 512
    int rd[9];
#pragma unroll
    for (int kg = 0; kg < 3; ++kg)
#pragma unroll
        for (int t = 0; t < 3; ++t) {
            int pix0 = (wid + kg) * 66 + lix + t;
            int sw = (pix0 & 3) ^ ((pix0 >> 2) & 3);
            rd[kg * 3 + t] = pix0 * 32 + ((lg ^ sw) << 3);
        }

    f32x4 acc[4][4];
#pragma unroll
    for (int i = 0; i < 4; ++i)
#pragma unroll
        for (int j = 0; j < 4; ++j) acc[i][j] = zero4();

    auto issue_in = [&](int cci, int buf) {
#pragma unroll
        for (int i = 0; i < 6; ++i) {
            int chunk = wid + 8 * i;
            if (chunk < 42) {
                const void* src = gok[i] ? (const void*)(in + goff[i] + cci * 32)
                                         : (const void*)zb;
                gll16(src, (char*)&in_lds[buf][0] + chunk * 1024);
            }
        }
    };
    auto issue_w = [&](int cci, int buf) {
#pragma unroll
        for (int i = 0; i < 5; ++i) {
            int chunk = wid + 8 * i;              // = kgt*4 + mi
            if (chunk < 36) {
                const bf16* src = wt + ((size_t)(chunk >> 2) * NC + cci) * 2048
                                     + (chunk & 3) * 512 + lane * 8;
                gll16(src, (char*)&w_lds[buf][0] + chunk * 1024);
            }
        }
    };
    // rotated-register pipelined compute: issue kgt+1's frag loads before
    // kgt's MFMAs; sched_barrier(0) pins the phase boundaries.
    auto compute = [&](int buf) {
        bf16x8 afA[4], bfA[4], afB[4], bfB[4];
#pragma unroll
        for (int mi = 0; mi < 4; ++mi)
            afA[mi] = *(const bf16x8*)&w_lds[buf][(0 * 4 + mi) * 512 + lane * 8];
#pragma unroll
        for (int nj = 0; nj < 4; ++nj)
            bfA[nj] = *(const bf16x8*)&in_lds[buf][rd[0] + nj * 512];
#pragma unroll
        for (int kgt = 0; kgt < 9; ++kgt) {
            bf16x8* afC = (kgt & 1) ? afB : afA;
            bf16x8* bfC = (kgt & 1) ? bfB : bfA;
            bf16x8* afN = (kgt & 1) ? afA : afB;
            bf16x8* bfN = (kgt & 1) ? bfA : bfB;
            if (kgt < 8) {
#pragma unroll
                for (int mi = 0; mi < 4; ++mi)
                    afN[mi] = *(const bf16x8*)&w_lds[buf][((kgt + 1) * 4 + mi) * 512 + lane * 8];
#pragma unroll
                for (int nj = 0; nj < 4; ++nj)
                    bfN[nj] = *(const bf16x8*)&in_lds[buf][rd[kgt + 1] + nj * 512];
            }
            __builtin_amdgcn_sched_barrier(0);
#pragma unroll
            for (int nj = 0; nj < 4; ++nj)
#pragma unroll
                for (int mi = 0; mi < 4; ++mi)
                    acc[mi][nj] = mfma16(afC[mi], bfC[nj], acc[mi][nj]);
            __builtin_amdgcn_sched_barrier(0);
        }
    };

    issue_in(0, 0);
    issue_w(0, 0);
#pragma unroll 1
    for (int c = 0; c < NC; ++c) {
        if (c + 1 < NC) {
            issue_in(c + 1, (c + 1) & 1);
            issue_w(c + 1, (c + 1) & 1);
            // wait for chunk c's loads only: chunk c+1's newest 11/10/9
            // stay in flight across the barrier (T4).
            if (wid < 2)      asm volatile("s_waitcnt vmcnt(11)" ::: "memory");
            else if (wid < 4) asm volatile("s_waitcnt vmcnt(10)" ::: "memory");
            else              asm volatile("s_waitcnt vmcnt(9)"  ::: "memory");
        } else {
            asm volatile("s_waitcnt vmcnt(0)" ::: "memory");
        }
        __builtin_amdgcn_s_barrier();           // raw: no implicit vmcnt drain
        __builtin_amdgcn_sched_barrier(0);
        compute(c & 1);
        __builtin_amdgcn_s_barrier();           // buf reusable next iteration
    }

    if (OUTMODE == 0) {
        // single-pass coalesced store: stage all 8 rows across both in bufs
        bf16* out = (bf16*)outp;
        bf16* stg = &in_lds[0][0];             // [8*64 px][68], 69,632 B
#pragma unroll
        for (int mi = 0; mi < 4; ++mi) {
            float A[4], Bc[4];
#pragma unroll
            for (int r = 0; r < 4; ++r) {
                int c = mi * 16 + lg * 4 + r;
                float s = bg[c] * rsqrtf(bv[c] + EPSV);
                A[r]  = s;
                Bc[r] = bias[c] * s + bb[c] - bm[c] * s;
            }
#pragma unroll
            for (int nj = 0; nj < 4; ++nj) {
                int px = nj * 16 + lix;
                bf16x4 vv;
#pragma unroll
                for (int r = 0; r < 4; ++r)
                    vv[r] = (bf16)(acc[mi][nj][r] * A[r] + Bc[r]);
                *(bf16x4*)&stg[(wid * 64 + px) * 68 + mi * 16 + lg * 4] = vv;
            }
        }
        __syncthreads();
#pragma unroll
        for (int k = 0; k < 8; ++k) {
            int idx = k * 512 + tid;           // 4096 16B-units
            int row = idx >> 9, rem = idx & 511;
            int px = rem >> 3, cu = rem & 7;
            bf16x8 vv = *(const bf16x8*)&stg[(row * 64 + px) * 68 + cu * 8];
            *(bf16x8*)&out[((size_t)((b * 128 + y0 + row) * 128)
                            + x0 + px) * 64 + cu * 8] = vv;
        }
        // fused q-gather: q[b][n][c] = h[b][4*(n/32)][4*(n%32)][c]
        if (qout && tid < 256) {
            int row4 = (tid >> 7) * 4;          // 0 or 4
            int rem  = tid & 127;               // 16 px4 * 8 cu
            int px4  = (rem >> 3) * 4, cu = rem & 7;
            int gy = y0 + row4, gx = x0 + px4;
            int n = ((gy >> 2) << 5) + (gx >> 2);
            bf16x8 vv = *(const bf16x8*)&stg[(row4 * 64 + px4) * 68 + cu * 8];
            *(bf16x8*)&qout[((size_t)(b * 1024 + n)) * 64 + cu * 8] = vv;
        }
    } else {
        float* out = (float*)outp;
        const int gy = y0 + wid;
#pragma unroll
        for (int mi = 0; mi < 4; ++mi) {
            float A[4], Bc[4];
#pragma unroll
            for (int r = 0; r < 4; ++r) {
                int c = mi * 16 + lg * 4 + r;
                float s = bg[c] * rsqrtf(bv[c] + EPSV);
                A[r]  = s;
                Bc[r] = bias[c] * s + bb[c] - bm[c] * s;
            }
#pragma unroll
            for (int nj = 0; nj < 4; ++nj) {
                int px = x0 + nj * 16 + lix;
                bf16x4 rv = *(const bf16x4*)&resid[((size_t)((b * 128 + gy) * 128) + px) * 64
                                                   + mi * 16 + lg * 4];
#pragma unroll
                for (int r = 0; r < 4; ++r) {
                    int c = mi * 16 + lg * 4 + r;
                    size_t oi = ((size_t)(b * 64 + c) << 14) + (gy << 7) + px;
                    out[oi] = acc[mi][nj][r] * A[r] + Bc[r] + (float)rv[r];
                }
            }
        }
    }
}

// ---------------------------------------------------------------------------
// Fused flash attention (unchanged).
// ---------------------------------------------------------------------------
__global__ __launch_bounds__(256) void attn_fused(const bf16* __restrict__ q,
                                                  bf16* __restrict__ o)
{
    __shared__ bf16 qn[64 * 72];
    __shared__ bf16 kn[128 * 72];
    __shared__ bf16 vt[64 * 136];
    __shared__ bf16 pl[4][16 * 136];
    __shared__ __align__(16) float fac[4][16];
    const int n0 = blockIdx.x * 64, b = blockIdx.y;
    const int tid = threadIdx.x, w = tid >> 6, lane = tid & 63;
    const int lix = lane & 15, lg = lane >> 4;
    const bf16* qb = q + ((size_t)b << 16);

    for (int f = tid; f < 512; f += 256) {
        int row = f >> 3, cu = f & 7;
        *(bf16x8*)&qn[row * 72 + cu * 8] =
            *(const bf16x8*)&qb[(size_t)(n0 + row) * 64 + cu * 8];
    }

    float m_run = -3.0e38f, l_run = 0.f;
    f32x4 oacc[4];
#pragma unroll
    for (int ct = 0; ct < 4; ++ct) oacc[ct] = zero4();

    for (int mt = 0; mt < 1024; mt += 128) {
        __syncthreads();
        for (int f = tid; f < 1024; f += 256) {
            int row = f >> 3, cu = f & 7;
            *(bf16x8*)&kn[row * 72 + cu * 8] =
                *(const bf16x8*)&qb[(size_t)(mt + row) * 64 + cu * 8];
        }
        for (int f = tid; f < 512; f += 256) {
            int mp = f >> 3, cu = f & 7;
            int m = mp * 2;
            bf16x8 a = *(const bf16x8*)&qb[(size_t)(mt + m) * 64 + cu * 8];
            bf16x8 c = *(const bf16x8*)&qb[(size_t)(mt + m + 1) * 64 + cu * 8];
#pragma unroll
            for (int j = 0; j < 8; ++j) {
                bf16x2 pr = {a[j], c[j]};
                *(bf16x2*)&vt[(cu * 8 + j) * 136 + m] = pr;
            }
        }
        __syncthreads();

        bf16x8 bq0 = *(const bf16x8*)&qn[(w * 16 + lix) * 72 + lg * 8];
        bf16x8 bq1 = *(const bf16x8*)&qn[(w * 16 + lix) * 72 + 32 + lg * 8];

        f32x4 s[8];
#pragma unroll
        for (int t = 0; t < 8; ++t) {
            bf16x8 a0 = *(const bf16x8*)&kn[(t * 16 + lix) * 72 + lg * 8];
            bf16x8 a1 = *(const bf16x8*)&kn[(t * 16 + lix) * 72 + 32 + lg * 8];
            s[t] = mfma16(a0, bq0, zero4());
            s[t] = mfma16(a1, bq1, s[t]);
        }

        float mx = -3.0e38f;
#pragma unroll
        for (int t = 0; t < 8; ++t)
#pragma unroll
            for (int r = 0; r < 4; ++r) { s[t][r] *= 0.125f; mx = fmaxf(mx, s[t][r]); }
        mx = fmaxf(mx, __shfl_xor(mx, 16));
        mx = fmaxf(mx, __shfl_xor(mx, 32));
        float m_new = fmaxf(m_run, mx);
        float alpha = __expf(m_run - m_new);

        float psum = 0.f;
#pragma unroll
        for (int t = 0; t < 8; ++t) {
            float p0 = __expf(s[t][0] - m_new), p1 = __expf(s[t][1] - m_new);
            float p2 = __expf(s[t][2] - m_new), p3 = __expf(s[t][3] - m_new);
            psum += (p0 + p1) + (p2 + p3);
            bf16x2 v01 = {(bf16)p0, (bf16)p1};
            bf16x2 v23 = {(bf16)p2, (bf16)p3};
            *(bf16x2*)&pl[w][lix * 136 + t * 16 + lg * 4]     = v01;
            *(bf16x2*)&pl[w][lix * 136 + t * 16 + lg * 4 + 2] = v23;
        }
        psum += __shfl_xor(psum, 16);
        psum += __shfl_xor(psum, 32);
        l_run = l_run * alpha + psum;
        m_run = m_new;
        if (lg == 0) fac[w][lix] = alpha;

        float4 a4 = *(const float4*)&fac[w][lg * 4];
        float aa[4] = {a4.x, a4.y, a4.z, a4.w};
#pragma unroll
        for (int ct = 0; ct < 4; ++ct)
#pragma unroll
            for (int r = 0; r < 4; ++r) oacc[ct][r] *= aa[r];

#pragma unroll
        for (int kk = 0; kk < 4; ++kk) {
            bf16x8 pa = *(const bf16x8*)&pl[w][lix * 136 + kk * 32 + lg * 8];
#pragma unroll
            for (int ct = 0; ct < 4; ++ct) {
                bf16x8 bv = *(const bf16x8*)&vt[(ct * 16 + lix) * 136 + kk * 32 + lg * 8];
                oacc[ct] = mfma16(pa, bv, oacc[ct]);
            }
        }
    }

    if (lg == 0) fac[w][lix] = l_run;
    float4 l4 = *(const float4*)&fac[w][lg * 4];
    float ll[4] = {1.f / l4.x, 1.f / l4.y, 1.f / l4.z, 1.f / l4.w};
#pragma unroll
    for (int ct = 0; ct < 4; ++ct)
#pragma unroll
        for (int r = 0; r < 4; ++r) {
            int n = n0 + w * 16 + lg * 4 + r;
            int c = ct * 16 + lix;
            o[((size_t)(b * 1024 + n)) * 64 + c] = (bf16)(oacc[ct][r] * ll[r]);
        }
}

// ---------------------------------------------------------------------------
// conv1x1 (128->128) + BN + fast exact GELU; coalesced store via LDS.
// ---------------------------------------------------------------------------
__global__ __launch_bounds__(256) void conv1x1_mfma(
    const bf16* __restrict__ h, const bf16* __restrict__ ov,
    const bf16* __restrict__ wt, const float* __restrict__ bias,
    const float* __restrict__ bg, const float* __restrict__ bb,
    const float* __restrict__ bm, const float* __restrict__ bv,
    bf16* __restrict__ g)
{
    __shared__ bf16 in1[128 * 136];           // 34,816 B (reused as out-stage)
    const int y = blockIdx.x, b = blockIdx.y;
    const int tid = threadIdx.x;
    const int wid = tid >> 6, lane = tid & 63;
    const int lix = lane & 15, lg = lane >> 4;
    const int wm = wid >> 1, wn = wid & 1;

    for (int f = tid; f < 128 * 16; f += 256) {
        int px = f >> 4, cu = f & 15;
        bf16x8 v;
        if (cu < 8) {
            v = *(const bf16x8*)&h[((size_t)((b * 128 + y) * 128 + px)) * 64 + cu * 8];
        } else {
            int n = ((y >> 2) << 5) + (px >> 2);
            v = *(const bf16x8*)&ov[((size_t)(b * 1024 + n)) * 64 + (cu - 8) * 8];
        }
        *(bf16x8*)&in1[px * 136 + cu * 8] = v;
    }
    __syncthreads();

    f32x4 acc[4][4];
#pragma unroll
    for (int i = 0; i < 4; ++i)
#pragma unroll
        for (int j = 0; j < 4; ++j) acc[i][j] = zero4();

#pragma unroll
    for (int ks = 0; ks < 4; ++ks) {
        bf16x8 af[4], bfv[4];
#pragma unroll
        for (int mi = 0; mi < 4; ++mi)
            af[mi] = *(const bf16x8*)&wt[(((size_t)(ks * 4 + lg) * 128) + wm * 64 + mi * 16 + lix) * 8];
#pragma unroll
        for (int nj = 0; nj < 4; ++nj)
            bfv[nj] = *(const bf16x8*)&in1[(wn * 64 + nj * 16 + lix) * 136 + ks * 32 + lg * 8];
#pragma unroll
        for (int mi = 0; mi < 4; ++mi)
#pragma unroll
            for (int nj = 0; nj < 4; ++nj)
                acc[mi][nj] = mfma16(af[mi], bfv[nj], acc[mi][nj]);
    }

    __syncthreads();                           // done reading in1
    bf16* stg = in1;                           // [128 px][132] view
#pragma unroll
    for (int mi = 0; mi < 4; ++mi) {
        float A[4], Bc[4];
#pragma unroll
        for (int r = 0; r < 4; ++r) {
            int c = wm * 64 + mi * 16 + lg * 4 + r;
            float s = bg[c] * rsqrtf(bv[c] + EPSV);
            A[r]  = s;
            Bc[r] = bias[c] * s + bb[c] - bm[c] * s;
        }
#pragma unroll
        for (int nj = 0; nj < 4; ++nj) {
            int px = wn * 64 + nj * 16 + lix;
            bf16x4 vv;
#pragma unroll
            for (int r = 0; r < 4; ++r)
                vv[r] = (bf16)gelu_f(acc[mi][nj][r] * A[r] + Bc[r]);
            *(bf16x4*)&stg[px * 132 + wm * 64 + mi * 16 + lg * 4] = vv;
        }
    }
    __syncthreads();
#pragma unroll
    for (int k = 0; k < 8; ++k) {
        int idx = k * 256 + tid;               // 2048 16B-units
        int px = idx >> 4, cu = idx & 15;
        bf16x8 v = *(const bf16x8*)&stg[px * 132 + cu * 8];
        *(bf16x8*)&g[((size_t)((b * 128 + y) * 128) + px) * 128 + cu * 8] = v;
    }
}

// ---------------------------------------------------------------------------
extern "C" void kernel_launch(void* const* d_in, const int* in_sizes, int n_in,
                              void* d_out, int out_size, void* d_ws, size_t ws_size,
                              hipStream_t stream)
{
    const float* x     = (const float*)d_in[0];
    const float* fc1_w = (const float*)d_in[1];
    const float* fc1_b = (const float*)d_in[2];
    const float* bn1_g = (const float*)d_in[3];
    const float* bn1_b = (const float*)d_in[4];
    const float* bn1_m = (const float*)d_in[5];
    const float* bn1_v = (const float*)d_in[6];
    const float* gc_w  = (const float*)d_in[7];
    const float* gc_b  = (const float*)d_in[8];
    const float* bng_g = (const float*)d_in[9];
    const float* bng_b = (const float*)d_in[10];
    const float* bng_m = (const float*)d_in[11];
    const float* bng_v = (const float*)d_in[12];
    const float* fc2_w = (const float*)d_in[13];
    const float* fc2_b = (const float*)d_in[14];
    const float* bn2_g = (const float*)d_in[15];
    const float* bn2_b = (const float*)d_in[16];
    const float* bn2_m = (const float*)d_in[17];
    const float* bn2_v = (const float*)d_in[18];

    char* wsb = (char*)d_ws;
    bf16* x_bf = (bf16*)wsb;                      // 33,554,432 B
    bf16* h    = (bf16*)(wsb + 33554432);         // 33,554,432 B
    bf16* g    = (bf16*)(wsb + 67108864);         // 67,108,864 B
    bf16* q    = (bf16*)(wsb + 134217728);        //  2,097,152 B
    bf16* o    = (bf16*)(wsb + 136314880);        //  2,097,152 B
    bf16* wt1  = (bf16*)(wsb + 138412032);        //     73,728 B
    bf16* wt2  = (bf16*)(wsb + 138485760);        //    147,456 B
    bf16* wtg  = (bf16*)(wsb + 138633216);        //     32,768 B
    bf16* zb   = (bf16*)(wsb + 138665984);        //      1,024 B

    prep_all<<<112, 256, 0, stream>>>(fc1_w, fc2_w, gc_w, wt1, wt2, wtg,
                                      (float*)zb);

    cvt_x_nhwc<<<dim3(256, 16), 256, 0, stream>>>(x, x_bf);

    conv3x3_mfma<64, 0><<<512, 512, 0, stream>>>(
        x_bf, wt1, fc1_b, bn1_g, bn1_b, bn1_m, bn1_v, nullptr, zb, h, q);

    attn_fused<<<dim3(16, 16), 256, 0, stream>>>(q, o);

    conv1x1_mfma<<<dim3(128, 16), 256, 0, stream>>>(
        h, o, wtg, gc_b, bng_g, bng_b, bng_m, bng_v, g);

    conv3x3_mfma<128, 1><<<512, 512, 0, stream>>>(
        g, wt2, fc2_b, bn2_g, bn2_b, bn2_m, bn2_v, x_bf, zb, (float*)d_out, nullptr);
}

// Round 15
// 173.522 us; speedup vs baseline: 1.1185x; 1.0340x over previous
//
#include <hip/hip_runtime.h>
#include <math.h>

#define EPSV 1e-5f

typedef __bf16 bf16;
using bf16x8 = __attribute__((ext_vector_type(8))) __bf16;
using bf16x4 = __attribute__((ext_vector_type(4))) __bf16;
using bf16x2 = __attribute__((ext_vector_type(2))) __bf16;
using f32x4  = __attribute__((ext_vector_type(4))) float;

static __device__ __forceinline__ f32x4 mfma16(bf16x8 a, bf16x8 b, f32x4 c) {
    return __builtin_amdgcn_mfma_f32_16x16x32_bf16(a, b, c, 0, 0, 0);
}
static __device__ __forceinline__ f32x4 zero4() {
    f32x4 z = {0.f, 0.f, 0.f, 0.f};
    return z;
}

// async global->LDS, 16B per lane. LDS dst = wave-uniform base + lane*16;
// global src is per-lane.
typedef __attribute__((address_space(1))) const char g_char_t;
typedef __attribute__((address_space(3))) char lds_char_t;
static __device__ __forceinline__ void gll16(const void* g, void* l) {
    __builtin_amdgcn_global_load_lds((g_char_t*)g, (lds_char_t*)l, 16, 0, 0);
}

// exact-GELU via Abramowitz-Stegun 7.1.26 erf (|err| <= 1.5e-7)
static __device__ __forceinline__ float gelu_f(float v) {
    float z = fabsf(v) * 0.70710678118f;
    float t = __builtin_amdgcn_rcpf(1.f + 0.3275911f * z);
    float poly = t * (0.254829592f + t * (-0.284496736f + t * (1.421413741f +
                 t * (-1.453152027f + t * 1.061405429f))));
    float e = __expf(-z * z);
    float erfv = copysignf(1.f - poly * e, v);
    return 0.5f * v * (1.f + erfv);
}

// ---------------------------------------------------------------------------
// Merged prep + x-convert (1 dispatch).
// bx <  4096 : x fp32 NCHW -> bf16 NHWC (LDS transpose, coalesced)
// bx >= 4096 : weight prep (conv3x3 lane-linear fragments; 1x1 frag-major)
//              + zb zeroing.
// ---------------------------------------------------------------------------
static __device__ __forceinline__ void prep3x3_one(const float* w, bf16* wt,
                                                   int t, int CIN)
{
    int cout = t / CIN, ci = t - cout * CIN;
    int cci = ci >> 5, lg = (ci >> 3) & 3, j = ci & 7;
    int mi = cout >> 4, lix = cout & 15;
#pragma unroll
    for (int kgt = 0; kgt < 9; ++kgt) {
        float v = w[(size_t)t * 9 + kgt];
        wt[((((size_t)kgt * (CIN >> 5) + cci) * 4 + mi) * 64 + lg * 16 + lix) * 8 + j]
            = (bf16)v;
    }
}

__global__ __launch_bounds__(256) void prep_cvt(
    const float* __restrict__ x, bf16* __restrict__ xb,
    const float* __restrict__ fc1_w, const float* __restrict__ fc2_w,
    const float* __restrict__ gc_w,
    bf16* __restrict__ wt1, bf16* __restrict__ wt2, bf16* __restrict__ wtg,
    float* __restrict__ zb)
{
    __shared__ float t_lds[64 * 68];
    const int bx = blockIdx.x, tid = threadIdx.x;
    if (bx < 4096) {
        const int b = bx >> 8, inner = bx & 255;
        const int y = inner >> 1, x0 = (inner & 1) * 64;
        for (int f = tid; f < 64 * 16; f += 256) {
            int c = f >> 4, xu = f & 15;
            float4 v = *(const float4*)&x[((size_t)(b * 64 + c) << 14) + (y << 7) + x0 + xu * 4];
            t_lds[(xu * 4 + 0) * 68 + c] = v.x;
            t_lds[(xu * 4 + 1) * 68 + c] = v.y;
            t_lds[(xu * 4 + 2) * 68 + c] = v.z;
            t_lds[(xu * 4 + 3) * 68 + c] = v.w;
        }
        __syncthreads();
        for (int f = tid; f < 64 * 8; f += 256) {
            int xx = f >> 3, cu = f & 7;
            const float* p = &t_lds[xx * 68 + cu * 8];
            bf16x8 v;
#pragma unroll
            for (int j = 0; j < 8; ++j) v[j] = (bf16)p[j];
            *(bf16x8*)&xb[((size_t)((b * 128 + y) * 128) + x0 + xx) * 64 + cu * 8] = v;
        }
    } else {
        int px = bx - 4096;
        if (px < 16) {
            prep3x3_one(fc1_w, wt1, px * 256 + tid, 64);
        } else if (px < 48) {
            prep3x3_one(fc2_w, wt2, (px - 16) * 256 + tid, 128);
        } else {
            if (px == 48 && tid < 64)
                ((float4*)zb)[tid] = make_float4(0.f, 0.f, 0.f, 0.f);
            int t = (px - 48) * 256 + tid;       // cout*128+ci, 16384
            int cout = t >> 7, ci = t & 127;
            int ks = ci >> 5, lg = (ci >> 3) & 3, j = ci & 7;
            wtg[(((size_t)(ks * 4 + lg) * 128) + cout) * 8 + j] = (bf16)gc_w[t];
        }
    }
}

// ---------------------------------------------------------------------------
// conv3x3 MFMA implicit GEMM (v11 structure - measured best). Unchanged.
// ---------------------------------------------------------------------------
template<int CIN, int OUTMODE>
__global__ __launch_bounds__(512) void conv3x3_mfma(
    const bf16* __restrict__ in, const bf16* __restrict__ wt,
    const float* __restrict__ bias,
    const float* __restrict__ bg, const float* __restrict__ bb,
    const float* __restrict__ bm, const float* __restrict__ bv,
    const bf16* __restrict__ resid, const bf16* __restrict__ zb,
    void* __restrict__ outp, bf16* __restrict__ qout)
{
    constexpr int NC = CIN >> 5;
    __shared__ bf16 in_lds[2][672 * 32];      // 86,016 B
    __shared__ bf16 w_lds[2][36 * 512];       // 73,728 B  (total 159,744)

    const int wg = blockIdx.x;                // 512 blocks
    const int v  = (wg & 7) * 64 + (wg >> 3); // bijective XCD chunking
    const int tile = v & 31, b = v >> 5;
    const int x0 = (tile & 1) * 64;
    const int y0 = (tile >> 1) * 8;
    const int tid  = threadIdx.x;
    const int wid  = tid >> 6;
    const int lane = tid & 63;
    const int lix  = lane & 15, lg = lane >> 4;

    int goff[6]; bool gok[6];
#pragma unroll
    for (int i = 0; i < 6; ++i) {
        int chunk = wid + 8 * i;
        int f = chunk * 64 + lane;
        int pix = f >> 2, u = f & 3;
        int sw = (pix & 3) ^ ((pix >> 2) & 3);
        int ug = u ^ sw;
        int iy = pix / 66, ix = pix - iy * 66;
        int gy = y0 + iy - 1, gx = x0 + ix - 1;
        gok[i]  = (chunk < 42) && (pix < 660) &&
                  (unsigned)gy < 128u && (unsigned)gx < 128u;
        goff[i] = ((b * 128 + gy) * 128 + gx) * CIN + ug * 8;
    }
    int rd[9];
#pragma unroll
    for (int kg = 0; kg < 3; ++kg)
#pragma unroll
        for (int t = 0; t < 3; ++t) {
            int pix0 = (wid + kg) * 66 + lix + t;
            int sw = (pix0 & 3) ^ ((pix0 >> 2) & 3);
            rd[kg * 3 + t] = pix0 * 32 + ((lg ^ sw) << 3);
        }

    f32x4 acc[4][4];
#pragma unroll
    for (int i = 0; i < 4; ++i)
#pragma unroll
        for (int j = 0; j < 4; ++j) acc[i][j] = zero4();

    auto issue_in = [&](int cci, int buf) {
#pragma unroll
        for (int i = 0; i < 6; ++i) {
            int chunk = wid + 8 * i;
            if (chunk < 42) {
                const void* src = gok[i] ? (const void*)(in + goff[i] + cci * 32)
                                         : (const void*)zb;
                gll16(src, (char*)&in_lds[buf][0] + chunk * 1024);
            }
        }
    };
    auto issue_w = [&](int cci, int buf) {
#pragma unroll
        for (int i = 0; i < 5; ++i) {
            int chunk = wid + 8 * i;              // = kgt*4 + mi
            if (chunk < 36) {
                const bf16* src = wt + ((size_t)(chunk >> 2) * NC + cci) * 2048
                                     + (chunk & 3) * 512 + lane * 8;
                gll16(src, (char*)&w_lds[buf][0] + chunk * 1024);
            }
        }
    };
    auto compute = [&](int buf) {
        bf16x8 afA[4], bfA[4], afB[4], bfB[4];
#pragma unroll
        for (int mi = 0; mi < 4; ++mi)
            afA[mi] = *(const bf16x8*)&w_lds[buf][(0 * 4 + mi) * 512 + lane * 8];
#pragma unroll
        for (int nj = 0; nj < 4; ++nj)
            bfA[nj] = *(const bf16x8*)&in_lds[buf][rd[0] + nj * 512];
#pragma unroll
        for (int kgt = 0; kgt < 9; ++kgt) {
            bf16x8* afC = (kgt & 1) ? afB : afA;
            bf16x8* bfC = (kgt & 1) ? bfB : bfA;
            bf16x8* afN = (kgt & 1) ? afA : afB;
            bf16x8* bfN = (kgt & 1) ? bfA : bfB;
            if (kgt < 8) {
#pragma unroll
                for (int mi = 0; mi < 4; ++mi)
                    afN[mi] = *(const bf16x8*)&w_lds[buf][((kgt + 1) * 4 + mi) * 512 + lane * 8];
#pragma unroll
                for (int nj = 0; nj < 4; ++nj)
                    bfN[nj] = *(const bf16x8*)&in_lds[buf][rd[kgt + 1] + nj * 512];
            }
            __builtin_amdgcn_sched_barrier(0);
#pragma unroll
            for (int nj = 0; nj < 4; ++nj)
#pragma unroll
                for (int mi = 0; mi < 4; ++mi)
                    acc[mi][nj] = mfma16(afC[mi], bfC[nj], acc[mi][nj]);
            __builtin_amdgcn_sched_barrier(0);
        }
    };

    issue_in(0, 0);
    issue_w(0, 0);
#pragma unroll 1
    for (int c = 0; c < NC; ++c) {
        if (c + 1 < NC) {
            issue_in(c + 1, (c + 1) & 1);
            issue_w(c + 1, (c + 1) & 1);
            if (wid < 2)      asm volatile("s_waitcnt vmcnt(11)" ::: "memory");
            else if (wid < 4) asm volatile("s_waitcnt vmcnt(10)" ::: "memory");
            else              asm volatile("s_waitcnt vmcnt(9)"  ::: "memory");
        } else {
            asm volatile("s_waitcnt vmcnt(0)" ::: "memory");
        }
        __builtin_amdgcn_s_barrier();           // raw: no implicit vmcnt drain
        __builtin_amdgcn_sched_barrier(0);
        compute(c & 1);
        __builtin_amdgcn_s_barrier();
    }

    if (OUTMODE == 0) {
        bf16* out = (bf16*)outp;
        bf16* stg = &in_lds[0][0];             // [8*64 px][68]
#pragma unroll
        for (int mi = 0; mi < 4; ++mi) {
            float A[4], Bc[4];
#pragma unroll
            for (int r = 0; r < 4; ++r) {
                int c = mi * 16 + lg * 4 + r;
                float s = bg[c] * rsqrtf(bv[c] + EPSV);
                A[r]  = s;
                Bc[r] = bias[c] * s + bb[c] - bm[c] * s;
            }
#pragma unroll
            for (int nj = 0; nj < 4; ++nj) {
                int px = nj * 16 + lix;
                bf16x4 vv;
#pragma unroll
                for (int r = 0; r < 4; ++r)
                    vv[r] = (bf16)(acc[mi][nj][r] * A[r] + Bc[r]);
                *(bf16x4*)&stg[(wid * 64 + px) * 68 + mi * 16 + lg * 4] = vv;
            }
        }
        __syncthreads();
#pragma unroll
        for (int k = 0; k < 8; ++k) {
            int idx = k * 512 + tid;
            int row = idx >> 9, rem = idx & 511;
            int px = rem >> 3, cu = rem & 7;
            bf16x8 vv = *(const bf16x8*)&stg[(row * 64 + px) * 68 + cu * 8];
            *(bf16x8*)&out[((size_t)((b * 128 + y0 + row) * 128)
                            + x0 + px) * 64 + cu * 8] = vv;
        }
        // fused q-gather
        if (qout && tid < 256) {
            int row4 = (tid >> 7) * 4;
            int rem  = tid & 127;
            int px4  = (rem >> 3) * 4, cu = rem & 7;
            int gy = y0 + row4, gx = x0 + px4;
            int n = ((gy >> 2) << 5) + (gx >> 2);
            bf16x8 vv = *(const bf16x8*)&stg[(row4 * 64 + px4) * 68 + cu * 8];
            *(bf16x8*)&qout[((size_t)(b * 1024 + n)) * 64 + cu * 8] = vv;
        }
    } else {
        float* out = (float*)outp;
        const int gy = y0 + wid;
#pragma unroll
        for (int mi = 0; mi < 4; ++mi) {
            float A[4], Bc[4];
#pragma unroll
            for (int r = 0; r < 4; ++r) {
                int c = mi * 16 + lg * 4 + r;
                float s = bg[c] * rsqrtf(bv[c] + EPSV);
                A[r]  = s;
                Bc[r] = bias[c] * s + bb[c] - bm[c] * s;
            }
#pragma unroll
            for (int nj = 0; nj < 4; ++nj) {
                int px = x0 + nj * 16 + lix;
                bf16x4 rv = *(const bf16x4*)&resid[((size_t)((b * 128 + gy) * 128) + px) * 64
                                                   + mi * 16 + lg * 4];
#pragma unroll
                for (int r = 0; r < 4; ++r) {
                    int c = mi * 16 + lg * 4 + r;
                    size_t oi = ((size_t)(b * 64 + c) << 14) + (gy << 7) + px;
                    out[oi] = acc[mi][nj][r] * A[r] + Bc[r] + (float)rv[r];
                }
            }
        }
    }
}

// ---------------------------------------------------------------------------
// Fused flash attention + conv1x1(128->128)+BN+GELU epilogue.
// Block (bx, b): 64 q-rows n0=bx*64 == full-res region rows [bx*8, bx*8+8),
// all 128 x. Main loop unchanged. Epilogue: o -> LDS; 16 px-groups of 64 px:
// prefetch h (gll16 dbuf, counted vmcnt, raw barriers), GEMM 64px x 128cout
// x K128 ([h;o]), BN+GELU, LDS-staged coalesced g store.
// ---------------------------------------------------------------------------
__global__ __launch_bounds__(256) void attn_fused(
    const bf16* __restrict__ q, const bf16* __restrict__ h,
    const bf16* __restrict__ wtg, const float* __restrict__ bias,
    const float* __restrict__ bg, const float* __restrict__ bb,
    const float* __restrict__ bm, const float* __restrict__ bv,
    bf16* __restrict__ g)
{
    __shared__ __align__(16) char smem[62976];
    bf16* qn = (bf16*)smem;                      //  9,216 B (64 x 72)
    bf16* kn = (bf16*)(smem + 9216);             // 18,432 B (128 x 72)
    bf16* vt = (bf16*)(smem + 27648);            // 17,408 B (64 x 136)
    bf16* pl = (bf16*)(smem + 45056);            // 17,408 B (4 x 16 x 136)
    float* fac = (float*)(smem + 62464);         //    256 B
    // epilogue overlay (after fence):
    bf16* o_lds = (bf16*)smem;                   //  9,216 B (64 x 72)
    bf16* h_lds = (bf16*)(smem + 9216);          // 16,384 B (2 x 64 x 64)
    bf16* g_lds = (bf16*)(smem + 25600);         // 16,896 B (64 x 132)

    const int n0 = blockIdx.x * 64, b = blockIdx.y;
    const int tid = threadIdx.x, w = tid >> 6, lane = tid & 63;
    const int lix = lane & 15, lg = lane >> 4;
    const bf16* qb = q + ((size_t)b << 16);

    for (int f = tid; f < 512; f += 256) {
        int row = f >> 3, cu = f & 7;
        *(bf16x8*)&qn[row * 72 + cu * 8] =
            *(const bf16x8*)&qb[(size_t)(n0 + row) * 64 + cu * 8];
    }

    float m_run = -3.0e38f, l_run = 0.f;
    f32x4 oacc[4];
#pragma unroll
    for (int ct = 0; ct < 4; ++ct) oacc[ct] = zero4();

    for (int mt = 0; mt < 1024; mt += 128) {
        __syncthreads();
        for (int f = tid; f < 1024; f += 256) {
            int row = f >> 3, cu = f & 7;
            *(bf16x8*)&kn[row * 72 + cu * 8] =
                *(const bf16x8*)&qb[(size_t)(mt + row) * 64 + cu * 8];
        }
        for (int f = tid; f < 512; f += 256) {
            int mp = f >> 3, cu = f & 7;
            int m = mp * 2;
            bf16x8 a = *(const bf16x8*)&qb[(size_t)(mt + m) * 64 + cu * 8];
            bf16x8 c = *(const bf16x8*)&qb[(size_t)(mt + m + 1) * 64 + cu * 8];
#pragma unroll
            for (int j = 0; j < 8; ++j) {
                bf16x2 pr = {a[j], c[j]};
                *(bf16x2*)&vt[(cu * 8 + j) * 136 + m] = pr;
            }
        }
        __syncthreads();

        bf16x8 bq0 = *(const bf16x8*)&qn[(w * 16 + lix) * 72 + lg * 8];
        bf16x8 bq1 = *(const bf16x8*)&qn[(w * 16 + lix) * 72 + 32 + lg * 8];

        f32x4 s[8];
#pragma unroll
        for (int t = 0; t < 8; ++t) {
            bf16x8 a0 = *(const bf16x8*)&kn[(t * 16 + lix) * 72 + lg * 8];
            bf16x8 a1 = *(const bf16x8*)&kn[(t * 16 + lix) * 72 + 32 + lg * 8];
            s[t] = mfma16(a0, bq0, zero4());
            s[t] = mfma16(a1, bq1, s[t]);
        }

        float mx = -3.0e38f;
#pragma unroll
        for (int t = 0; t < 8; ++t)
#pragma unroll
            for (int r = 0; r < 4; ++r) { s[t][r] *= 0.125f; mx = fmaxf(mx, s[t][r]); }
        mx = fmaxf(mx, __shfl_xor(mx, 16));
        mx = fmaxf(mx, __shfl_xor(mx, 32));
        float m_new = fmaxf(m_run, mx);
        float alpha = __expf(m_run - m_new);

        float psum = 0.f;
#pragma unroll
        for (int t = 0; t < 8; ++t) {
            float p0 = __expf(s[t][0] - m_new), p1 = __expf(s[t][1] - m_new);
            float p2 = __expf(s[t][2] - m_new), p3 = __expf(s[t][3] - m_new);
            psum += (p0 + p1) + (p2 + p3);
            bf16x2 v01 = {(bf16)p0, (bf16)p1};
            bf16x2 v23 = {(bf16)p2, (bf16)p3};
            *(bf16x2*)&pl[w * 2176 + lix * 136 + t * 16 + lg * 4]     = v01;
            *(bf16x2*)&pl[w * 2176 + lix * 136 + t * 16 + lg * 4 + 2] = v23;
        }
        psum += __shfl_xor(psum, 16);
        psum += __shfl_xor(psum, 32);
        l_run = l_run * alpha + psum;
        m_run = m_new;
        if (lg == 0) fac[w * 16 + lix] = alpha;

        float4 a4 = *(const float4*)&fac[w * 16 + lg * 4];
        float aa[4] = {a4.x, a4.y, a4.z, a4.w};
#pragma unroll
        for (int ct = 0; ct < 4; ++ct)
#pragma unroll
            for (int r = 0; r < 4; ++r) oacc[ct][r] *= aa[r];

#pragma unroll
        for (int kk = 0; kk < 4; ++kk) {
            bf16x8 pa = *(const bf16x8*)&pl[w * 2176 + lix * 136 + kk * 32 + lg * 8];
#pragma unroll
            for (int ct = 0; ct < 4; ++ct) {
                bf16x8 bv = *(const bf16x8*)&vt[(ct * 16 + lix) * 136 + kk * 32 + lg * 8];
                oacc[ct] = mfma16(pa, bv, oacc[ct]);
            }
        }
    }

    if (lg == 0) fac[w * 16 + lix] = l_run;
    float4 l4 = *(const float4*)&fac[w * 16 + lg * 4];
    float ll[4] = {1.f / l4.x, 1.f / l4.y, 1.f / l4.z, 1.f / l4.w};

    // ---- fence main-loop LDS, then overlay: o -> o_lds ----
    __syncthreads();
#pragma unroll
    for (int ct = 0; ct < 4; ++ct)
#pragma unroll
        for (int r = 0; r < 4; ++r) {
            int nl = w * 16 + lg * 4 + r;
            o_lds[nl * 72 + ct * 16 + lix] = (bf16)(oacc[ct][r] * ll[r]);
        }
    __syncthreads();

    // ---- fused conv1x1 + BN + GELU ----
    const int ybase = n0 >> 3;                   // block's first full-res row
    const int sxor = (lix >> 2) & 3;             // h-LDS read swizzle

    // BN coefs for this wave's 32 couts (c = w*32 + mi*16 + lg*4 + r)
    float A2[2][4], B2[2][4];
#pragma unroll
    for (int mi = 0; mi < 2; ++mi)
#pragma unroll
        for (int r = 0; r < 4; ++r) {
            int c = w * 32 + mi * 16 + lg * 4 + r;
            float s = bg[c] * rsqrtf(bv[c] + EPSV);
            A2[mi][r] = s;
            B2[mi][r] = bias[c] * s + bb[c] - bm[c] * s;
        }

    auto issue_h = [&](int pg, int buf) {
        int y = ybase + (pg >> 1), xg = (pg & 1) * 64;
#pragma unroll
        for (int i = 0; i < 2; ++i) {
            int ch = w * 2 + i;                  // 8 chunks of 1KB
            int px = ch * 8 + (lane >> 3);
            int cu = lane & 7;
            int cus = cu ^ ((px >> 2) & 3);      // pre-swizzle source
            const bf16* src = &h[((size_t)((b * 128 + y) * 128) + xg + px) * 64 + cus * 8];
            gll16(src, (char*)h_lds + buf * 8192 + ch * 1024);
        }
    };

    issue_h(0, 0);
#pragma unroll 1
    for (int pg = 0; pg < 16; ++pg) {
        if (pg < 15) {
            issue_h(pg + 1, (pg + 1) & 1);
            asm volatile("s_waitcnt vmcnt(2)" ::: "memory");
        } else {
            asm volatile("s_waitcnt vmcnt(0)" ::: "memory");
        }
        __builtin_amdgcn_s_barrier();

        const int buf = pg & 1;
        const int nlb = (pg >> 3) * 32 + (pg & 1) * 16 + (lix >> 2);

        f32x4 a2[2][4];
#pragma unroll
        for (int mi = 0; mi < 2; ++mi)
#pragma unroll
            for (int nj = 0; nj < 4; ++nj) a2[mi][nj] = zero4();

#pragma unroll
        for (int ks = 0; ks < 4; ++ks) {
            bf16x8 af0 = *(const bf16x8*)&wtg[(((size_t)(ks * 4 + lg) * 128)
                                               + w * 32 + lix) * 8];
            bf16x8 af1 = *(const bf16x8*)&wtg[(((size_t)(ks * 4 + lg) * 128)
                                               + w * 32 + 16 + lix) * 8];
#pragma unroll
            for (int nj = 0; nj < 4; ++nj) {
                bf16x8 bfv;
                if (ks < 2) {
                    int px = nj * 16 + lix;
                    bfv = *(const bf16x8*)&h_lds[buf * 4096 + px * 64
                                                 + ((ks * 4 + (lg ^ sxor)) << 3)];
                } else {
                    int nl = nlb + nj * 4;
                    bfv = *(const bf16x8*)&o_lds[nl * 72 + (((ks - 2) * 4 + lg) << 3)];
                }
                a2[0][nj] = mfma16(af0, bfv, a2[0][nj]);
                a2[1][nj] = mfma16(af1, bfv, a2[1][nj]);
            }
        }

        // BN + GELU -> g_lds [64 px][132]
#pragma unroll
        for (int mi = 0; mi < 2; ++mi)
#pragma unroll
            for (int nj = 0; nj < 4; ++nj) {
                int px = nj * 16 + lix;
                bf16x4 vv;
#pragma unroll
                for (int r = 0; r < 4; ++r)
                    vv[r] = (bf16)gelu_f(a2[mi][nj][r] * A2[mi][r] + B2[mi][r]);
                *(bf16x4*)&g_lds[px * 132 + w * 32 + mi * 16 + lg * 4] = vv;
            }
        __builtin_amdgcn_s_barrier();

        // coalesced store: 64 px x 128 c = 1024 16B-units
        {
            int y = ybase + (pg >> 1), xg = (pg & 1) * 64;
#pragma unroll
            for (int k = 0; k < 4; ++k) {
                int idx = k * 256 + tid;
                int px = idx >> 4, cu = idx & 15;
                bf16x8 vv = *(const bf16x8*)&g_lds[px * 132 + cu * 8];
                *(bf16x8*)&g[((size_t)((b * 128 + y) * 128) + xg + px) * 128 + cu * 8] = vv;
            }
        }
        __builtin_amdgcn_s_barrier();           // g_lds reusable next group
    }
}

// ---------------------------------------------------------------------------
extern "C" void kernel_launch(void* const* d_in, const int* in_sizes, int n_in,
                              void* d_out, int out_size, void* d_ws, size_t ws_size,
                              hipStream_t stream)
{
    const float* x     = (const float*)d_in[0];
    const float* fc1_w = (const float*)d_in[1];
    const float* fc1_b = (const float*)d_in[2];
    const float* bn1_g = (const float*)d_in[3];
    const float* bn1_b = (const float*)d_in[4];
    const float* bn1_m = (const float*)d_in[5];
    const float* bn1_v = (const float*)d_in[6];
    const float* gc_w  = (const float*)d_in[7];
    const float* gc_b  = (const float*)d_in[8];
    const float* bng_g = (const float*)d_in[9];
    const float* bng_b = (const float*)d_in[10];
    const float* bng_m = (const float*)d_in[11];
    const float* bng_v = (const float*)d_in[12];
    const float* fc2_w = (const float*)d_in[13];
    const float* fc2_b = (const float*)d_in[14];
    const float* bn2_g = (const float*)d_in[15];
    const float* bn2_b = (const float*)d_in[16];
    const float* bn2_m = (const float*)d_in[17];
    const float* bn2_v = (const float*)d_in[18];

    char* wsb = (char*)d_ws;
    bf16* x_bf = (bf16*)wsb;                      // 33,554,432 B
    bf16* h    = (bf16*)(wsb + 33554432);         // 33,554,432 B
    bf16* g    = (bf16*)(wsb + 67108864);         // 67,108,864 B
    bf16* q    = (bf16*)(wsb + 134217728);        //  2,097,152 B
    bf16* wt1  = (bf16*)(wsb + 136314880);        //     73,728 B
    bf16* wt2  = (bf16*)(wsb + 136388608);        //    147,456 B
    bf16* wtg  = (bf16*)(wsb + 136536064);        //     32,768 B
    bf16* zb   = (bf16*)(wsb + 136568832);        //      1,024 B

    prep_cvt<<<4208, 256, 0, stream>>>(x, x_bf, fc1_w, fc2_w, gc_w,
                                       wt1, wt2, wtg, (float*)zb);

    conv3x3_mfma<64, 0><<<512, 512, 0, stream>>>(
        x_bf, wt1, fc1_b, bn1_g, bn1_b, bn1_m, bn1_v, nullptr, zb, h, q);

    attn_fused<<<dim3(16, 16), 256, 0, stream>>>(
        q, h, wtg, gc_b, bng_g, bng_b, bng_m, bng_v, g);

    conv3x3_mfma<128, 1><<<512, 512, 0, stream>>>(
        g, wt2, fc2_b, bn2_g, bn2_b, bn2_m, bn2_v, x_bf, zb, (float*)d_out, nullptr);
}

// Round 16
// 159.444 us; speedup vs baseline: 1.2173x; 1.0883x over previous
//
#include <hip/hip_runtime.h>
#include <math.h>

#define EPSV 1e-5f

typedef __bf16 bf16;
using bf16x8 = __attribute__((ext_vector_type(8))) __bf16;
using bf16x4 = __attribute__((ext_vector_type(4))) __bf16;
using bf16x2 = __attribute__((ext_vector_type(2))) __bf16;
using f32x4  = __attribute__((ext_vector_type(4))) float;

static __device__ __forceinline__ f32x4 mfma16(bf16x8 a, bf16x8 b, f32x4 c) {
    return __builtin_amdgcn_mfma_f32_16x16x32_bf16(a, b, c, 0, 0, 0);
}
static __device__ __forceinline__ f32x4 zero4() {
    f32x4 z = {0.f, 0.f, 0.f, 0.f};
    return z;
}

// async global->LDS, 16B per lane. LDS dst = wave-uniform base + lane*16;
// global src is per-lane.
typedef __attribute__((address_space(1))) const char g_char_t;
typedef __attribute__((address_space(3))) char lds_char_t;
static __device__ __forceinline__ void gll16(const void* g, void* l) {
    __builtin_amdgcn_global_load_lds((g_char_t*)g, (lds_char_t*)l, 16, 0, 0);
}

// exact-GELU via Abramowitz-Stegun 7.1.26 erf (|err| <= 1.5e-7)
static __device__ __forceinline__ float gelu_f(float v) {
    float z = fabsf(v) * 0.70710678118f;
    float t = __builtin_amdgcn_rcpf(1.f + 0.3275911f * z);
    float poly = t * (0.254829592f + t * (-0.284496736f + t * (1.421413741f +
                 t * (-1.453152027f + t * 1.061405429f))));
    float e = __expf(-z * z);
    float erfv = copysignf(1.f - poly * e, v);
    return 0.5f * v * (1.f + erfv);
}

// ---------------------------------------------------------------------------
// Merged prep + x-convert (1 dispatch).
// ---------------------------------------------------------------------------
static __device__ __forceinline__ void prep3x3_one(const float* w, bf16* wt,
                                                   int t, int CIN)
{
    int cout = t / CIN, ci = t - cout * CIN;
    int cci = ci >> 5, lg = (ci >> 3) & 3, j = ci & 7;
    int mi = cout >> 4, lix = cout & 15;
#pragma unroll
    for (int kgt = 0; kgt < 9; ++kgt) {
        float v = w[(size_t)t * 9 + kgt];
        wt[((((size_t)kgt * (CIN >> 5) + cci) * 4 + mi) * 64 + lg * 16 + lix) * 8 + j]
            = (bf16)v;
    }
}

__global__ __launch_bounds__(256) void prep_cvt(
    const float* __restrict__ x, bf16* __restrict__ xb,
    const float* __restrict__ fc1_w, const float* __restrict__ fc2_w,
    const float* __restrict__ gc_w,
    bf16* __restrict__ wt1, bf16* __restrict__ wt2, bf16* __restrict__ wtg,
    float* __restrict__ zb)
{
    __shared__ float t_lds[64 * 68];
    const int bx = blockIdx.x, tid = threadIdx.x;
    if (bx < 4096) {
        const int b = bx >> 8, inner = bx & 255;
        const int y = inner >> 1, x0 = (inner & 1) * 64;
        for (int f = tid; f < 64 * 16; f += 256) {
            int c = f >> 4, xu = f & 15;
            float4 v = *(const float4*)&x[((size_t)(b * 64 + c) << 14) + (y << 7) + x0 + xu * 4];
            t_lds[(xu * 4 + 0) * 68 + c] = v.x;
            t_lds[(xu * 4 + 1) * 68 + c] = v.y;
            t_lds[(xu * 4 + 2) * 68 + c] = v.z;
            t_lds[(xu * 4 + 3) * 68 + c] = v.w;
        }
        __syncthreads();
        for (int f = tid; f < 64 * 8; f += 256) {
            int xx = f >> 3, cu = f & 7;
            const float* p = &t_lds[xx * 68 + cu * 8];
            bf16x8 v;
#pragma unroll
            for (int j = 0; j < 8; ++j) v[j] = (bf16)p[j];
            *(bf16x8*)&xb[((size_t)((b * 128 + y) * 128) + x0 + xx) * 64 + cu * 8] = v;
        }
    } else {
        int px = bx - 4096;
        if (px < 16) {
            prep3x3_one(fc1_w, wt1, px * 256 + tid, 64);
        } else if (px < 48) {
            prep3x3_one(fc2_w, wt2, (px - 16) * 256 + tid, 128);
        } else {
            if (px == 48 && tid < 64)
                ((float4*)zb)[tid] = make_float4(0.f, 0.f, 0.f, 0.f);
            int t = (px - 48) * 256 + tid;       // cout*128+ci, 16384
            int cout = t >> 7, ci = t & 127;
            int ks = ci >> 5, lg = (ci >> 3) & 3, j = ci & 7;
            wtg[(((size_t)(ks * 4 + lg) * 128) + cout) * 8 + j] = (bf16)gc_w[t];
        }
    }
}

// ---------------------------------------------------------------------------
// conv3x3 MFMA implicit GEMM (v11 structure - measured best). Unchanged.
// ---------------------------------------------------------------------------
template<int CIN, int OUTMODE>
__global__ __launch_bounds__(512) void conv3x3_mfma(
    const bf16* __restrict__ in, const bf16* __restrict__ wt,
    const float* __restrict__ bias,
    const float* __restrict__ bg, const float* __restrict__ bb,
    const float* __restrict__ bm, const float* __restrict__ bv,
    const bf16* __restrict__ resid, const bf16* __restrict__ zb,
    void* __restrict__ outp, bf16* __restrict__ qout)
{
    constexpr int NC = CIN >> 5;
    __shared__ bf16 in_lds[2][672 * 32];      // 86,016 B
    __shared__ bf16 w_lds[2][36 * 512];       // 73,728 B  (total 159,744)

    const int wg = blockIdx.x;                // 512 blocks
    const int v  = (wg & 7) * 64 + (wg >> 3); // bijective XCD chunking
    const int tile = v & 31, b = v >> 5;
    const int x0 = (tile & 1) * 64;
    const int y0 = (tile >> 1) * 8;
    const int tid  = threadIdx.x;
    const int wid  = tid >> 6;
    const int lane = tid & 63;
    const int lix  = lane & 15, lg = lane >> 4;

    int goff[6]; bool gok[6];
#pragma unroll
    for (int i = 0; i < 6; ++i) {
        int chunk = wid + 8 * i;
        int f = chunk * 64 + lane;
        int pix = f >> 2, u = f & 3;
        int sw = (pix & 3) ^ ((pix >> 2) & 3);
        int ug = u ^ sw;
        int iy = pix / 66, ix = pix - iy * 66;
        int gy = y0 + iy - 1, gx = x0 + ix - 1;
        gok[i]  = (chunk < 42) && (pix < 660) &&
                  (unsigned)gy < 128u && (unsigned)gx < 128u;
        goff[i] = ((b * 128 + gy) * 128 + gx) * CIN + ug * 8;
    }
    int rd[9];
#pragma unroll
    for (int kg = 0; kg < 3; ++kg)
#pragma unroll
        for (int t = 0; t < 3; ++t) {
            int pix0 = (wid + kg) * 66 + lix + t;
            int sw = (pix0 & 3) ^ ((pix0 >> 2) & 3);
            rd[kg * 3 + t] = pix0 * 32 + ((lg ^ sw) << 3);
        }

    f32x4 acc[4][4];
#pragma unroll
    for (int i = 0; i < 4; ++i)
#pragma unroll
        for (int j = 0; j < 4; ++j) acc[i][j] = zero4();

    auto issue_in = [&](int cci, int buf) {
#pragma unroll
        for (int i = 0; i < 6; ++i) {
            int chunk = wid + 8 * i;
            if (chunk < 42) {
                const void* src = gok[i] ? (const void*)(in + goff[i] + cci * 32)
                                         : (const void*)zb;
                gll16(src, (char*)&in_lds[buf][0] + chunk * 1024);
            }
        }
    };
    auto issue_w = [&](int cci, int buf) {
#pragma unroll
        for (int i = 0; i < 5; ++i) {
            int chunk = wid + 8 * i;              // = kgt*4 + mi
            if (chunk < 36) {
                const bf16* src = wt + ((size_t)(chunk >> 2) * NC + cci) * 2048
                                     + (chunk & 3) * 512 + lane * 8;
                gll16(src, (char*)&w_lds[buf][0] + chunk * 1024);
            }
        }
    };
    auto compute = [&](int buf) {
        bf16x8 afA[4], bfA[4], afB[4], bfB[4];
#pragma unroll
        for (int mi = 0; mi < 4; ++mi)
            afA[mi] = *(const bf16x8*)&w_lds[buf][(0 * 4 + mi) * 512 + lane * 8];
#pragma unroll
        for (int nj = 0; nj < 4; ++nj)
            bfA[nj] = *(const bf16x8*)&in_lds[buf][rd[0] + nj * 512];
#pragma unroll
        for (int kgt = 0; kgt < 9; ++kgt) {
            bf16x8* afC = (kgt & 1) ? afB : afA;
            bf16x8* bfC = (kgt & 1) ? bfB : bfA;
            bf16x8* afN = (kgt & 1) ? afA : afB;
            bf16x8* bfN = (kgt & 1) ? bfA : bfB;
            if (kgt < 8) {
#pragma unroll
                for (int mi = 0; mi < 4; ++mi)
                    afN[mi] = *(const bf16x8*)&w_lds[buf][((kgt + 1) * 4 + mi) * 512 + lane * 8];
#pragma unroll
                for (int nj = 0; nj < 4; ++nj)
                    bfN[nj] = *(const bf16x8*)&in_lds[buf][rd[kgt + 1] + nj * 512];
            }
            __builtin_amdgcn_sched_barrier(0);
#pragma unroll
            for (int nj = 0; nj < 4; ++nj)
#pragma unroll
                for (int mi = 0; mi < 4; ++mi)
                    acc[mi][nj] = mfma16(afC[mi], bfC[nj], acc[mi][nj]);
            __builtin_amdgcn_sched_barrier(0);
        }
    };

    issue_in(0, 0);
    issue_w(0, 0);
#pragma unroll 1
    for (int c = 0; c < NC; ++c) {
        if (c + 1 < NC) {
            issue_in(c + 1, (c + 1) & 1);
            issue_w(c + 1, (c + 1) & 1);
            if (wid < 2)      asm volatile("s_waitcnt vmcnt(11)" ::: "memory");
            else if (wid < 4) asm volatile("s_waitcnt vmcnt(10)" ::: "memory");
            else              asm volatile("s_waitcnt vmcnt(9)"  ::: "memory");
        } else {
            asm volatile("s_waitcnt vmcnt(0)" ::: "memory");
        }
        __builtin_amdgcn_s_barrier();           // raw: no implicit vmcnt drain
        __builtin_amdgcn_sched_barrier(0);
        compute(c & 1);
        __builtin_amdgcn_s_barrier();
    }

    if (OUTMODE == 0) {
        bf16* out = (bf16*)outp;
        bf16* stg = &in_lds[0][0];             // [8*64 px][68]
#pragma unroll
        for (int mi = 0; mi < 4; ++mi) {
            float A[4], Bc[4];
#pragma unroll
            for (int r = 0; r < 4; ++r) {
                int c = mi * 16 + lg * 4 + r;
                float s = bg[c] * rsqrtf(bv[c] + EPSV);
                A[r]  = s;
                Bc[r] = bias[c] * s + bb[c] - bm[c] * s;
            }
#pragma unroll
            for (int nj = 0; nj < 4; ++nj) {
                int px = nj * 16 + lix;
                bf16x4 vv;
#pragma unroll
                for (int r = 0; r < 4; ++r)
                    vv[r] = (bf16)(acc[mi][nj][r] * A[r] + Bc[r]);
                *(bf16x4*)&stg[(wid * 64 + px) * 68 + mi * 16 + lg * 4] = vv;
            }
        }
        __syncthreads();
#pragma unroll
        for (int k = 0; k < 8; ++k) {
            int idx = k * 512 + tid;
            int row = idx >> 9, rem = idx & 511;
            int px = rem >> 3, cu = rem & 7;
            bf16x8 vv = *(const bf16x8*)&stg[(row * 64 + px) * 68 + cu * 8];
            *(bf16x8*)&out[((size_t)((b * 128 + y0 + row) * 128)
                            + x0 + px) * 64 + cu * 8] = vv;
        }
        // fused q-gather
        if (qout && tid < 256) {
            int row4 = (tid >> 7) * 4;
            int rem  = tid & 127;
            int px4  = (rem >> 3) * 4, cu = rem & 7;
            int gy = y0 + row4, gx = x0 + px4;
            int n = ((gy >> 2) << 5) + (gx >> 2);
            bf16x8 vv = *(const bf16x8*)&stg[(row4 * 64 + px4) * 68 + cu * 8];
            *(bf16x8*)&qout[((size_t)(b * 1024 + n)) * 64 + cu * 8] = vv;
        }
    } else {
        float* out = (float*)outp;
        const int gy = y0 + wid;
#pragma unroll
        for (int mi = 0; mi < 4; ++mi) {
            float A[4], Bc[4];
#pragma unroll
            for (int r = 0; r < 4; ++r) {
                int c = mi * 16 + lg * 4 + r;
                float s = bg[c] * rsqrtf(bv[c] + EPSV);
                A[r]  = s;
                Bc[r] = bias[c] * s + bb[c] - bm[c] * s;
            }
#pragma unroll
            for (int nj = 0; nj < 4; ++nj) {
                int px = x0 + nj * 16 + lix;
                bf16x4 rv = *(const bf16x4*)&resid[((size_t)((b * 128 + gy) * 128) + px) * 64
                                                   + mi * 16 + lg * 4];
#pragma unroll
                for (int r = 0; r < 4; ++r) {
                    int c = mi * 16 + lg * 4 + r;
                    size_t oi = ((size_t)(b * 64 + c) << 14) + (gy << 7) + px;
                    out[oi] = acc[mi][nj][r] * A[r] + Bc[r] + (float)rv[r];
                }
            }
        }
    }
}

// ---------------------------------------------------------------------------
// Fused flash attention (split-K, 2 teams of 4 waves) + conv1x1 epilogue
// (8 waves, one full row per iteration).
// Team t processes keys [t*512, t*512+512) with private K/V LDS + own
// online-softmax state; flash-combine merge through f32 LDS.
// ---------------------------------------------------------------------------
__global__ __launch_bounds__(512) void attn_fused(
    const bf16* __restrict__ q, const bf16* __restrict__ h,
    const bf16* __restrict__ wtg, const float* __restrict__ bias,
    const float* __restrict__ bg, const float* __restrict__ bb,
    const float* __restrict__ bm, const float* __restrict__ bv,
    bf16* __restrict__ g)
{
    __shared__ __align__(16) char smem[116224];
    // main phase:
    //   qn   [0,      9216)   64 x 72 bf16
    //   kn_t [9216  + t*18432, +18432)  128 x 72 bf16
    //   vt_t [46080 + t*17408, +17408)  64 x 136 bf16
    //   pl_w [80896 + w*4352,  +4352)   16 x 136 bf16
    //   fac_w[115712 + w*64,   +64)     16 f32
    // merge/epilogue overlay:
    //   o1   [0, 16384)       64 x 64 f32
    //   m0/l0/m1/l1 [16384, 17408)
    //   o_lds[17408, 26624)   64 x 72 bf16
    //   h_lds[26624, 59392)   2 x 128 x 64 bf16
    //   g_lds[59392, 93184)   128 x 132 bf16
    const int n0 = blockIdx.x * 64, b = blockIdx.y;
    const int tid = threadIdx.x, w = tid >> 6, lane = tid & 63;
    const int wl = w & 3, team = w >> 2, ttid = tid & 255;
    const int lix = lane & 15, lg = lane >> 4;
    const bf16* qb = q + ((size_t)b << 16);

    bf16*  qn  = (bf16*)smem;
    bf16*  kn  = (bf16*)(smem + 9216 + team * 18432);
    bf16*  vt  = (bf16*)(smem + 46080 + team * 17408);
    bf16*  pl  = (bf16*)(smem + 80896 + w * 4352);
    float* fac = (float*)(smem + 115712 + w * 64);

    {   // stage q: 512 units, 1/thread
        int row = tid >> 3, cu = tid & 7;
        *(bf16x8*)&qn[row * 72 + cu * 8] =
            *(const bf16x8*)&qb[(size_t)(n0 + row) * 64 + cu * 8];
    }

    float m_run = -3.0e38f, l_run = 0.f;
    f32x4 oacc[4];
#pragma unroll
    for (int ct = 0; ct < 4; ++ct) oacc[ct] = zero4();

    const bf16* qteam = qb + ((size_t)team << 9) * 64;   // team's key base
#pragma unroll 1
    for (int mt = 0; mt < 512; mt += 128) {
        __syncthreads();
        for (int f = ttid; f < 1024; f += 256) {
            int row = f >> 3, cu = f & 7;
            *(bf16x8*)&kn[row * 72 + cu * 8] =
                *(const bf16x8*)&qteam[(size_t)(mt + row) * 64 + cu * 8];
        }
        for (int f = ttid; f < 512; f += 256) {
            int mp = f >> 3, cu = f & 7;
            int m = mp * 2;
            bf16x8 a = *(const bf16x8*)&qteam[(size_t)(mt + m) * 64 + cu * 8];
            bf16x8 c = *(const bf16x8*)&qteam[(size_t)(mt + m + 1) * 64 + cu * 8];
#pragma unroll
            for (int j = 0; j < 8; ++j) {
                bf16x2 pr = {a[j], c[j]};
                *(bf16x2*)&vt[(cu * 8 + j) * 136 + m] = pr;
            }
        }
        __syncthreads();

        bf16x8 bq0 = *(const bf16x8*)&qn[(wl * 16 + lix) * 72 + lg * 8];
        bf16x8 bq1 = *(const bf16x8*)&qn[(wl * 16 + lix) * 72 + 32 + lg * 8];

        f32x4 s[8];
#pragma unroll
        for (int t = 0; t < 8; ++t) {
            bf16x8 a0 = *(const bf16x8*)&kn[(t * 16 + lix) * 72 + lg * 8];
            bf16x8 a1 = *(const bf16x8*)&kn[(t * 16 + lix) * 72 + 32 + lg * 8];
            s[t] = mfma16(a0, bq0, zero4());
            s[t] = mfma16(a1, bq1, s[t]);
        }

        float mx = -3.0e38f;
#pragma unroll
        for (int t = 0; t < 8; ++t)
#pragma unroll
            for (int r = 0; r < 4; ++r) { s[t][r] *= 0.125f; mx = fmaxf(mx, s[t][r]); }
        mx = fmaxf(mx, __shfl_xor(mx, 16));
        mx = fmaxf(mx, __shfl_xor(mx, 32));
        float m_new = fmaxf(m_run, mx);
        float alpha = __expf(m_run - m_new);

        float psum = 0.f;
#pragma unroll
        for (int t = 0; t < 8; ++t) {
            float p0 = __expf(s[t][0] - m_new), p1 = __expf(s[t][1] - m_new);
            float p2 = __expf(s[t][2] - m_new), p3 = __expf(s[t][3] - m_new);
            psum += (p0 + p1) + (p2 + p3);
            bf16x2 v01 = {(bf16)p0, (bf16)p1};
            bf16x2 v23 = {(bf16)p2, (bf16)p3};
            *(bf16x2*)&pl[lix * 136 + t * 16 + lg * 4]     = v01;
            *(bf16x2*)&pl[lix * 136 + t * 16 + lg * 4 + 2] = v23;
        }
        psum += __shfl_xor(psum, 16);
        psum += __shfl_xor(psum, 32);
        l_run = l_run * alpha + psum;
        m_run = m_new;
        if (lg == 0) fac[lix] = alpha;

        float4 a4 = *(const float4*)&fac[lg * 4];
        float aa[4] = {a4.x, a4.y, a4.z, a4.w};
#pragma unroll
        for (int ct = 0; ct < 4; ++ct)
#pragma unroll
            for (int r = 0; r < 4; ++r) oacc[ct][r] *= aa[r];

#pragma unroll
        for (int kk = 0; kk < 4; ++kk) {
            bf16x8 pa = *(const bf16x8*)&pl[lix * 136 + kk * 32 + lg * 8];
#pragma unroll
            for (int ct = 0; ct < 4; ++ct) {
                bf16x8 bv = *(const bf16x8*)&vt[(ct * 16 + lix) * 136 + kk * 32 + lg * 8];
                oacc[ct] = mfma16(pa, bv, oacc[ct]);
            }
        }
    }

    // ---- flash-combine merge of the two teams ----
    __syncthreads();                         // main-phase LDS dead
    float* o1  = (float*)smem;               // [64][64]
    float* m0l = (float*)(smem + 16384);
    float* l0l = m0l + 64;
    float* m1l = m0l + 128;
    float* l1l = m0l + 192;
    bf16*  o_lds = (bf16*)(smem + 17408);    // [64][72]

    if (lg == 0) {
        if (team == 0) { m0l[wl * 16 + lix] = m_run; l0l[wl * 16 + lix] = l_run; }
        else           { m1l[wl * 16 + lix] = m_run; l1l[wl * 16 + lix] = l_run; }
    }
    if (team == 1) {
#pragma unroll
        for (int ct = 0; ct < 4; ++ct)
#pragma unroll
            for (int r = 0; r < 4; ++r)
                o1[(wl * 16 + lg * 4 + r) * 64 + ct * 16 + lix] = oacc[ct][r];
    }
    __syncthreads();
    if (team == 0) {
        float4 m0v = *(const float4*)&m0l[wl * 16 + lg * 4];
        float4 l0v = *(const float4*)&l0l[wl * 16 + lg * 4];
        float4 m1v = *(const float4*)&m1l[wl * 16 + lg * 4];
        float4 l1v = *(const float4*)&l1l[wl * 16 + lg * 4];
        float m0a[4] = {m0v.x, m0v.y, m0v.z, m0v.w};
        float l0a[4] = {l0v.x, l0v.y, l0v.z, l0v.w};
        float m1a[4] = {m1v.x, m1v.y, m1v.z, m1v.w};
        float l1a[4] = {l1v.x, l1v.y, l1v.z, l1v.w};
        float a0[4], a1[4], inv[4];
#pragma unroll
        for (int r = 0; r < 4; ++r) {
            float mm = fmaxf(m0a[r], m1a[r]);
            a0[r] = __expf(m0a[r] - mm);
            a1[r] = __expf(m1a[r] - mm);
            inv[r] = 1.f / (l0a[r] * a0[r] + l1a[r] * a1[r]);
        }
#pragma unroll
        for (int ct = 0; ct < 4; ++ct)
#pragma unroll
            for (int r = 0; r < 4; ++r) {
                int nl = wl * 16 + lg * 4 + r;
                float ov = o1[nl * 64 + ct * 16 + lix];
                o_lds[nl * 72 + ct * 16 + lix] =
                    (bf16)((oacc[ct][r] * a0[r] + ov * a1[r]) * inv[r]);
            }
    }
    __syncthreads();

    // ---- fused conv1x1 + BN + GELU, 8 waves, 1 row (128px x 128c)/iter ----
    const int ybase = n0 >> 3;
    const int wc = w & 3;                    // cout quarter
    const int p2 = w >> 2;                   // px half
    bf16* h_lds = (bf16*)(smem + 26624);     // 2 x [128 px][64 c]
    bf16* g_lds = (bf16*)(smem + 59392);     // [128 px][132]

    float A2[2][4], B2[2][4];
#pragma unroll
    for (int mi = 0; mi < 2; ++mi)
#pragma unroll
        for (int r = 0; r < 4; ++r) {
            int c = wc * 32 + mi * 16 + lg * 4 + r;
            float s = bg[c] * rsqrtf(bv[c] + EPSV);
            A2[mi][r] = s;
            B2[mi][r] = bias[c] * s + bb[c] - bm[c] * s;
        }

    auto issue_h = [&](int pg, int buf) {
        int y = ybase + pg;
#pragma unroll
        for (int i = 0; i < 2; ++i) {
            int ch = w * 2 + i;              // 16 chunks of 1KB
            int px = ch * 8 + (lane >> 3);
            int cu = lane & 7;
            int cus = cu ^ (px & 7);         // pre-swizzle source (3-bit)
            const bf16* src = &h[((size_t)((b * 128 + y) * 128) + px) * 64 + cus * 8];
            gll16(src, (char*)h_lds + buf * 16384 + ch * 1024);
        }
    };

    issue_h(0, 0);
#pragma unroll 1
    for (int pg = 0; pg < 8; ++pg) {
        if (pg < 7) {
            issue_h(pg + 1, (pg + 1) & 1);
            asm volatile("s_waitcnt vmcnt(2)" ::: "memory");
        } else {
            asm volatile("s_waitcnt vmcnt(0)" ::: "memory");
        }
        __builtin_amdgcn_s_barrier();

        const int buf = pg & 1;
        const int nlb = (pg >> 2) * 32 + p2 * 16 + (lix >> 2);

        f32x4 a2[2][4];
#pragma unroll
        for (int mi = 0; mi < 2; ++mi)
#pragma unroll
            for (int nj = 0; nj < 4; ++nj) a2[mi][nj] = zero4();

#pragma unroll
        for (int ks = 0; ks < 4; ++ks) {
            bf16x8 af0 = *(const bf16x8*)&wtg[(((size_t)(ks * 4 + lg) * 128)
                                               + wc * 32 + lix) * 8];
            bf16x8 af1 = *(const bf16x8*)&wtg[(((size_t)(ks * 4 + lg) * 128)
                                               + wc * 32 + 16 + lix) * 8];
#pragma unroll
            for (int nj = 0; nj < 4; ++nj) {
                bf16x8 bfv;
                if (ks < 2) {
                    int px = p2 * 64 + nj * 16 + lix;
                    int slot = (ks * 4 + lg) ^ (px & 7);
                    bfv = *(const bf16x8*)&h_lds[buf * 8192 + px * 64 + slot * 8];
                } else {
                    int nl = nlb + nj * 4;
                    bfv = *(const bf16x8*)&o_lds[nl * 72 + (((ks - 2) * 4 + lg) << 3)];
                }
                a2[0][nj] = mfma16(af0, bfv, a2[0][nj]);
                a2[1][nj] = mfma16(af1, bfv, a2[1][nj]);
            }
        }

        // BN + GELU -> g_lds [128 px][132]
#pragma unroll
        for (int mi = 0; mi < 2; ++mi)
#pragma unroll
            for (int nj = 0; nj < 4; ++nj) {
                int px = p2 * 64 + nj * 16 + lix;
                bf16x4 vv;
#pragma unroll
                for (int r = 0; r < 4; ++r)
                    vv[r] = (bf16)gelu_f(a2[mi][nj][r] * A2[mi][r] + B2[mi][r]);
                *(bf16x4*)&g_lds[px * 132 + wc * 32 + mi * 16 + lg * 4] = vv;
            }
        __builtin_amdgcn_s_barrier();

        // coalesced store: 128 px x 128 c = 2048 16B-units, 512 thr
        {
            int y = ybase + pg;
#pragma unroll
            for (int k = 0; k < 4; ++k) {
                int idx = k * 512 + tid;
                int px = idx >> 4, cu = idx & 15;
                bf16x8 vv = *(const bf16x8*)&g_lds[px * 132 + cu * 8];
                *(bf16x8*)&g[((size_t)((b * 128 + y) * 128) + px) * 128 + cu * 8] = vv;
            }
        }
        __builtin_amdgcn_s_barrier();           // g_lds reusable next row
    }
}

// ---------------------------------------------------------------------------
extern "C" void kernel_launch(void* const* d_in, const int* in_sizes, int n_in,
                              void* d_out, int out_size, void* d_ws, size_t ws_size,
                              hipStream_t stream)
{
    const float* x     = (const float*)d_in[0];
    const float* fc1_w = (const float*)d_in[1];
    const float* fc1_b = (const float*)d_in[2];
    const float* bn1_g = (const float*)d_in[3];
    const float* bn1_b = (const float*)d_in[4];
    const float* bn1_m = (const float*)d_in[5];
    const float* bn1_v = (const float*)d_in[6];
    const float* gc_w  = (const float*)d_in[7];
    const float* gc_b  = (const float*)d_in[8];
    const float* bng_g = (const float*)d_in[9];
    const float* bng_b = (const float*)d_in[10];
    const float* bng_m = (const float*)d_in[11];
    const float* bng_v = (const float*)d_in[12];
    const float* fc2_w = (const float*)d_in[13];
    const float* fc2_b = (const float*)d_in[14];
    const float* bn2_g = (const float*)d_in[15];
    const float* bn2_b = (const float*)d_in[16];
    const float* bn2_m = (const float*)d_in[17];
    const float* bn2_v = (const float*)d_in[18];

    char* wsb = (char*)d_ws;
    bf16* x_bf = (bf16*)wsb;                      // 33,554,432 B
    bf16* h    = (bf16*)(wsb + 33554432);         // 33,554,432 B
    bf16* g    = (bf16*)(wsb + 67108864);         // 67,108,864 B
    bf16* q    = (bf16*)(wsb + 134217728);        //  2,097,152 B
    bf16* wt1  = (bf16*)(wsb + 136314880);        //     73,728 B
    bf16* wt2  = (bf16*)(wsb + 136388608);        //    147,456 B
    bf16* wtg  = (bf16*)(wsb + 136536064);        //     32,768 B
    bf16* zb   = (bf16*)(wsb + 136568832);        //      1,024 B

    prep_cvt<<<4208, 256, 0, stream>>>(x, x_bf, fc1_w, fc2_w, gc_w,
                                       wt1, wt2, wtg, (float*)zb);

    conv3x3_mfma<64, 0><<<512, 512, 0, stream>>>(
        x_bf, wt1, fc1_b, bn1_g, bn1_b, bn1_m, bn1_v, nullptr, zb, h, q);

    attn_fused<<<dim3(16, 16), 512, 0, stream>>>(
        q, h, wtg, gc_b, bng_g, bng_b, bng_m, bng_v, g);

    conv3x3_mfma<128, 1><<<512, 512, 0, stream>>>(
        g, wt2, fc2_b, bn2_g, bn2_b, bn2_m, bn2_v, x_bf, zb, (float*)d_out, nullptr);
}